// Round 1
// baseline (908.118 us; speedup 1.0000x reference)
//
#include <hip/hip_runtime.h>

#define DIM 64

// ---------- wave helpers (wave64) ----------
static __device__ __forceinline__ float bcast_lane(float v, int l) {
    return __uint_as_float(__builtin_amdgcn_readlane(__float_as_uint(v), l));
}

static __device__ __forceinline__ float wave_sum64(float v) {
    v += __shfl_xor(v, 1, 64);
    v += __shfl_xor(v, 2, 64);
    v += __shfl_xor(v, 4, 64);
    v += __shfl_xor(v, 8, 64);
    v += __shfl_xor(v, 16, 64);
    v += __shfl_xor(v, 32, 64);
    return v;
}

// ---------- CSR build ----------
__global__ void k_hist(const int* __restrict__ dst, int* __restrict__ cnt, int E) {
    int e = blockIdx.x * blockDim.x + threadIdx.x;
    if (e < E) atomicAdd(&cnt[dst[e]], 1);
}

// single-block chunked inclusive scan; also writes cursor[i] = row_start[i]
__global__ void k_scan(const int* __restrict__ cnt, int* __restrict__ row_start,
                       int* __restrict__ cursor, int n) {
    __shared__ int buf[1024];
    __shared__ int carry_s;
    int t = threadIdx.x;
    if (t == 0) { carry_s = 0; row_start[0] = 0; }
    __syncthreads();
    for (int base = 0; base < n; base += 1024) {
        int v = (base + t < n) ? cnt[base + t] : 0;
        buf[t] = v;
        __syncthreads();
        for (int off = 1; off < 1024; off <<= 1) {
            int x = (t >= off) ? buf[t - off] : 0;
            __syncthreads();
            buf[t] += x;
            __syncthreads();
        }
        int carry = carry_s;
        if (base + t < n) {
            int incl = buf[t] + carry;
            row_start[base + t + 1] = incl;
            cursor[base + t] = incl - v;   // exclusive prefix = row start
        }
        __syncthreads();
        if (t == 0) carry_s = carry + buf[1023];
        __syncthreads();
    }
}

__global__ void k_fill(const int* __restrict__ src, const int* __restrict__ dst,
                       int* __restrict__ cursor, int* __restrict__ csr_src, int E) {
    int e = blockIdx.x * blockDim.x + threadIdx.x;
    if (e < E) {
        int p = atomicAdd(&cursor[dst[e]], 1);
        csr_src[p] = src[e];
    }
}

// ---------- Phase A: per-node pre-op + 64x64 GEMV (+post-op), write h[node][mode*64+lane] ----------
// mode 0: euclidean (identity pre)
// mode 1: hyperbolic (log-map at origin scale pre)
// mode 2: spherical (normalize pre, normalize post)
__global__ __launch_bounds__(256) void k_phaseA(const float* __restrict__ X,
                                                const float* __restrict__ W,
                                                const float* __restrict__ bias,
                                                float* __restrict__ h,
                                                int mode,
                                                const float* __restrict__ curv,
                                                int n) {
    int gtid = blockIdx.x * blockDim.x + threadIdx.x;
    int wid  = gtid >> 6;   // node index (one wave per node)
    int lane = gtid & 63;
    if (wid >= n) return;

    // each lane holds weight row `lane`: w[k] = W[lane*64 + k]
    float w[DIM];
    const float4* Wv = reinterpret_cast<const float4*>(W + lane * DIM);
#pragma unroll
    for (int q = 0; q < DIM / 4; ++q) {
        float4 t = Wv[q];
        w[4 * q + 0] = t.x; w[4 * q + 1] = t.y;
        w[4 * q + 2] = t.z; w[4 * q + 3] = t.w;
    }

    float x = X[(size_t)wid * DIM + lane];

    if (mode == 1) {
        float c = curv[0];
        float sc = sqrtf(c);
        float n2 = wave_sum64(x * x);
        float dn = fmaxf(sqrtf(n2), 1e-10f);
        float scale = (2.0f / sc) * atanhf(sc * dn) / dn;
        x *= scale;
    } else if (mode == 2) {
        float n2 = wave_sum64(x * x);
        float nr = fmaxf(sqrtf(n2), 1e-12f);
        x /= nr;
    }

    // out[lane] = sum_k x[k] * W[lane][k] + bias[lane]
    float a0 = bias[lane], a1 = 0.f, a2 = 0.f, a3 = 0.f;
#pragma unroll
    for (int k = 0; k < DIM; k += 4) {
        a0 = fmaf(bcast_lane(x, k + 0), w[k + 0], a0);
        a1 = fmaf(bcast_lane(x, k + 1), w[k + 1], a1);
        a2 = fmaf(bcast_lane(x, k + 2), w[k + 2], a2);
        a3 = fmaf(bcast_lane(x, k + 3), w[k + 3], a3);
    }
    float acc = (a0 + a1) + (a2 + a3);

    if (mode == 2) {
        float n2 = wave_sum64(acc * acc);
        float nr = fmaxf(sqrtf(n2), 1e-12f);
        acc /= nr;
    }

    h[(size_t)wid * (3 * DIM) + mode * DIM + lane] = acc;
}

// ---------- Phase B: mean-aggregate all 3 manifolds + epilogues ----------
__global__ __launch_bounds__(256) void k_phaseB(const float* __restrict__ h,
                                                const int* __restrict__ row_start,
                                                const int* __restrict__ csr_src,
                                                float* __restrict__ e_out,
                                                float* __restrict__ b_out,
                                                float* __restrict__ s_out,
                                                const float* __restrict__ curv,
                                                int n) {
    int gtid = blockIdx.x * blockDim.x + threadIdx.x;
    int wid  = gtid >> 6;
    int lane = gtid & 63;
    if (wid >= n) return;

    int beg = row_start[wid];
    int end = row_start[wid + 1];

    float a0 = 0.f, a1 = 0.f, a2 = 0.f;
    int sidx = (beg < end) ? csr_src[beg] : 0;
    for (int j = beg; j < end; ++j) {
        int nxt = (j + 1 < end) ? csr_src[j + 1] : 0;   // prefetch next index
        const float* hp = h + (size_t)sidx * (3 * DIM);
        a0 += hp[lane];
        a1 += hp[DIM + lane];
        a2 += hp[2 * DIM + lane];
        sidx = nxt;
    }

    int cnt = end - beg;
    float inv = 1.0f / (float)(cnt > 0 ? cnt : 1);
    a0 *= inv; a1 *= inv; a2 *= inv;

    // euclidean: LeakyReLU(0.2)
    e_out[(size_t)wid * DIM + lane] = (a0 >= 0.f) ? a0 : 0.2f * a0;

    // hyperbolic: exp map at origin
    float c = curv[0];
    float sc = sqrtf(c);
    float vn = fmaxf(sqrtf(wave_sum64(a1 * a1)), 1e-10f);
    float scale = tanhf(sc * vn * 0.5f) / (sc * vn);
    b_out[(size_t)wid * DIM + lane] = a1 * scale;

    // spherical: normalize
    float nr = fmaxf(sqrtf(wave_sum64(a2 * a2)), 1e-12f);
    s_out[(size_t)wid * DIM + lane] = a2 / nr;
}

extern "C" void kernel_launch(void* const* d_in, const int* in_sizes, int n_in,
                              void* d_out, int out_size, void* d_ws, size_t ws_size,
                              hipStream_t stream) {
    const float* e0   = (const float*)d_in[0];
    const float* b0   = (const float*)d_in[1];
    const float* s0   = (const float*)d_in[2];
    const float* We   = (const float*)d_in[3];
    const float* be   = (const float*)d_in[4];
    const float* Wb   = (const float*)d_in[5];
    const float* bb   = (const float*)d_in[6];
    const float* Ws   = (const float*)d_in[7];
    const float* bs   = (const float*)d_in[8];
    const float* bcur = (const float*)d_in[9];
    const int*   src  = (const int*)d_in[11];
    const int*   dst  = (const int*)d_in[12];

    const int N = in_sizes[0] / DIM;
    const int E = in_sizes[11];
    const int L = in_sizes[3] / (DIM * DIM);

    // workspace carve
    const int Npad = (N + 63) & ~63;
    int* cnt       = (int*)d_ws;                 // N
    int* row_start = cnt + Npad;                 // N+1
    int* cursor    = row_start + Npad + 64;      // N
    int* csr_src   = cursor + Npad;              // E
    float* h       = (float*)(csr_src + ((E + 63) & ~63));  // N*192

    float* out_e = (float*)d_out;
    float* out_b = out_e + (size_t)N * DIM;
    float* out_s = out_b + (size_t)N * DIM;

    // ---- build CSR (once per call; reused by both layers) ----
    hipMemsetAsync(cnt, 0, (size_t)N * sizeof(int), stream);
    {
        int blk = 256, grd = (E + blk - 1) / blk;
        k_hist<<<grd, blk, 0, stream>>>(dst, cnt, E);
        k_scan<<<1, 1024, 0, stream>>>(cnt, row_start, cursor, N);
        k_fill<<<grd, blk, 0, stream>>>(src, dst, cursor, csr_src, E);
    }

    const int blkA = 256;
    const int grdA = (N * DIM + blkA - 1) / blkA;  // one wave per node

    for (int l = 0; l < L; ++l) {
        const float* Xe = (l == 0) ? e0 : out_e;
        const float* Xb = (l == 0) ? b0 : out_b;
        const float* Xs = (l == 0) ? s0 : out_s;
        const float* Wl;
        const float* bl;

        Wl = We + (size_t)l * DIM * DIM; bl = be + (size_t)l * DIM;
        k_phaseA<<<grdA, blkA, 0, stream>>>(Xe, Wl, bl, h, 0, bcur, N);
        Wl = Wb + (size_t)l * DIM * DIM; bl = bb + (size_t)l * DIM;
        k_phaseA<<<grdA, blkA, 0, stream>>>(Xb, Wl, bl, h, 1, bcur, N);
        Wl = Ws + (size_t)l * DIM * DIM; bl = bs + (size_t)l * DIM;
        k_phaseA<<<grdA, blkA, 0, stream>>>(Xs, Wl, bl, h, 2, bcur, N);

        k_phaseB<<<grdA, blkA, 0, stream>>>(h, row_start, csr_src,
                                            out_e, out_b, out_s, bcur, N);
    }
}

// Round 2
// 423.510 us; speedup vs baseline: 2.1443x; 2.1443x over previous
//
#include <hip/hip_runtime.h>

#define DIM 64

// ---------- wave helpers (wave64) ----------
static __device__ __forceinline__ float bcast_lane(float v, int l) {
    return __uint_as_float(__builtin_amdgcn_readlane(__float_as_uint(v), l));
}

static __device__ __forceinline__ float wave_sum64(float v) {
    v += __shfl_xor(v, 1, 64);
    v += __shfl_xor(v, 2, 64);
    v += __shfl_xor(v, 4, 64);
    v += __shfl_xor(v, 8, 64);
    v += __shfl_xor(v, 16, 64);
    v += __shfl_xor(v, 32, 64);
    return v;
}

// ---------- CSR build ----------
__global__ void k_hist(const int* __restrict__ dst, int* __restrict__ cnt, int E) {
    int e = blockIdx.x * blockDim.x + threadIdx.x;
    if (e < E) atomicAdd(&cnt[dst[e]], 1);
}

// hierarchical scan, step 1: per-block inclusive scan of 1024-chunks
__global__ __launch_bounds__(1024) void k_scan1(const int* __restrict__ cnt,
                                                int* __restrict__ partial,
                                                int* __restrict__ blocksum, int n) {
    __shared__ int buf[1024];
    int t = threadIdx.x;
    int i = blockIdx.x * 1024 + t;
    int v = (i < n) ? cnt[i] : 0;
    buf[t] = v;
    __syncthreads();
    for (int off = 1; off < 1024; off <<= 1) {
        int x = (t >= off) ? buf[t - off] : 0;
        __syncthreads();
        buf[t] += x;
        __syncthreads();
    }
    if (i < n) partial[i] = buf[t];           // inclusive within block
    if (t == 1023) blocksum[blockIdx.x] = buf[1023];
}

// step 2: single-block inclusive scan of block sums (nb <= 1024)
__global__ __launch_bounds__(1024) void k_scan2(int* __restrict__ blocksum, int nb) {
    __shared__ int buf[1024];
    int t = threadIdx.x;
    buf[t] = (t < nb) ? blocksum[t] : 0;
    __syncthreads();
    for (int off = 1; off < 1024; off <<= 1) {
        int x = (t >= off) ? buf[t - off] : 0;
        __syncthreads();
        buf[t] += x;
        __syncthreads();
    }
    if (t < nb) blocksum[t] = buf[t];
}

// step 3: fixup -> row_start (exclusive+1), cursor (row start)
__global__ void k_scan3(const int* __restrict__ partial, const int* __restrict__ blocksum,
                        const int* __restrict__ cnt,
                        int* __restrict__ row_start, int* __restrict__ cursor, int n) {
    int i = blockIdx.x * blockDim.x + threadIdx.x;
    if (i == 0) row_start[0] = 0;
    if (i < n) {
        int b = i >> 10;
        int add = (b > 0) ? blocksum[b - 1] : 0;
        int incl = partial[i] + add;
        row_start[i + 1] = incl;
        cursor[i] = incl - cnt[i];
    }
}

__global__ void k_fill(const int* __restrict__ src, const int* __restrict__ dst,
                       int* __restrict__ cursor, int* __restrict__ csr_src, int E) {
    int e = blockIdx.x * blockDim.x + threadIdx.x;
    if (e < E) {
        int p = atomicAdd(&cursor[dst[e]], 1);
        csr_src[p] = src[e];
    }
}

// ---------- Phase A (fused 3 manifolds): pre-op + 64x64 GEMV (+post-op) ----------
// grid-stride over nodes so the per-wave 16KB weight register fill amortizes.
__global__ __launch_bounds__(256) void k_phaseA3(
        const float* __restrict__ Xe, const float* __restrict__ Xb, const float* __restrict__ Xs,
        const float* __restrict__ We, const float* __restrict__ be,
        const float* __restrict__ Wb, const float* __restrict__ bb,
        const float* __restrict__ Ws, const float* __restrict__ bs,
        float* __restrict__ h, const float* __restrict__ curv,
        int n, int totalWaves) {
    int gtid = blockIdx.x * blockDim.x + threadIdx.x;
    int gw   = gtid >> 6;
    int lane = gtid & 63;
    float c  = curv[0];
    float sc = sqrtf(c);

    for (int mode = 0; mode < 3; ++mode) {
        const float* W    = (mode == 0) ? We : (mode == 1) ? Wb : Ws;
        const float* bias = (mode == 0) ? be : (mode == 1) ? bb : bs;
        const float* X    = (mode == 0) ? Xe : (mode == 1) ? Xb : Xs;

        // lane holds weight row `lane`
        float w[DIM];
        const float4* Wv = reinterpret_cast<const float4*>(W + lane * DIM);
#pragma unroll
        for (int q = 0; q < DIM / 4; ++q) {
            float4 t = Wv[q];
            w[4 * q + 0] = t.x; w[4 * q + 1] = t.y;
            w[4 * q + 2] = t.z; w[4 * q + 3] = t.w;
        }
        float bl = bias[lane];

        for (int node = gw; node < n; node += totalWaves) {
            float x = X[(size_t)node * DIM + lane];

            if (mode == 1) {
                float n2 = wave_sum64(x * x);
                float dn = fmaxf(sqrtf(n2), 1e-10f);
                float scale = (2.0f / sc) * atanhf(sc * dn) / dn;
                x *= scale;
            } else if (mode == 2) {
                float n2 = wave_sum64(x * x);
                float nr = fmaxf(sqrtf(n2), 1e-12f);
                x /= nr;
            }

            float a0 = bl, a1 = 0.f, a2 = 0.f, a3 = 0.f;
#pragma unroll
            for (int k = 0; k < DIM; k += 4) {
                a0 = fmaf(bcast_lane(x, k + 0), w[k + 0], a0);
                a1 = fmaf(bcast_lane(x, k + 1), w[k + 1], a1);
                a2 = fmaf(bcast_lane(x, k + 2), w[k + 2], a2);
                a3 = fmaf(bcast_lane(x, k + 3), w[k + 3], a3);
            }
            float acc = (a0 + a1) + (a2 + a3);

            if (mode == 2) {
                float n2 = wave_sum64(acc * acc);
                float nr = fmaxf(sqrtf(n2), 1e-12f);
                acc /= nr;
            }

            h[(size_t)node * (3 * DIM) + mode * DIM + lane] = acc;
        }
    }
}

// ---------- Phase B: mean-aggregate all 3 manifolds + epilogues ----------
__global__ __launch_bounds__(256) void k_phaseB(const float* __restrict__ h,
                                                const int* __restrict__ row_start,
                                                const int* __restrict__ csr_src,
                                                float* __restrict__ e_out,
                                                float* __restrict__ b_out,
                                                float* __restrict__ s_out,
                                                const float* __restrict__ curv,
                                                int n) {
    int gtid = blockIdx.x * blockDim.x + threadIdx.x;
    int wid  = gtid >> 6;
    int lane = gtid & 63;
    if (wid >= n) return;

    int beg = row_start[wid];
    int end = row_start[wid + 1];

    float a0 = 0.f, a1 = 0.f, a2 = 0.f;
    float c0 = 0.f, c1 = 0.f, c2 = 0.f;
    int j = beg;
    for (; j + 1 < end; j += 2) {
        int s0 = csr_src[j];
        int s1 = csr_src[j + 1];
        const float* h0 = h + (size_t)s0 * (3 * DIM);
        const float* h1 = h + (size_t)s1 * (3 * DIM);
        float t0 = h0[lane], t1 = h0[DIM + lane], t2 = h0[2 * DIM + lane];
        float u0 = h1[lane], u1 = h1[DIM + lane], u2 = h1[2 * DIM + lane];
        a0 += t0; a1 += t1; a2 += t2;
        c0 += u0; c1 += u1; c2 += u2;
    }
    if (j < end) {
        int s0 = csr_src[j];
        const float* h0 = h + (size_t)s0 * (3 * DIM);
        a0 += h0[lane]; a1 += h0[DIM + lane]; a2 += h0[2 * DIM + lane];
    }
    a0 += c0; a1 += c1; a2 += c2;

    int cnt = end - beg;
    float inv = 1.0f / (float)(cnt > 0 ? cnt : 1);
    a0 *= inv; a1 *= inv; a2 *= inv;

    // euclidean: LeakyReLU(0.2)
    e_out[(size_t)wid * DIM + lane] = (a0 >= 0.f) ? a0 : 0.2f * a0;

    // hyperbolic: exp map at origin
    float c = curv[0];
    float sc = sqrtf(c);
    float vn = fmaxf(sqrtf(wave_sum64(a1 * a1)), 1e-10f);
    float scale = tanhf(sc * vn * 0.5f) / (sc * vn);
    b_out[(size_t)wid * DIM + lane] = a1 * scale;

    // spherical: normalize
    float nr = fmaxf(sqrtf(wave_sum64(a2 * a2)), 1e-12f);
    s_out[(size_t)wid * DIM + lane] = a2 / nr;
}

extern "C" void kernel_launch(void* const* d_in, const int* in_sizes, int n_in,
                              void* d_out, int out_size, void* d_ws, size_t ws_size,
                              hipStream_t stream) {
    const float* e0   = (const float*)d_in[0];
    const float* b0   = (const float*)d_in[1];
    const float* s0   = (const float*)d_in[2];
    const float* We   = (const float*)d_in[3];
    const float* be   = (const float*)d_in[4];
    const float* Wb   = (const float*)d_in[5];
    const float* bb   = (const float*)d_in[6];
    const float* Ws   = (const float*)d_in[7];
    const float* bs   = (const float*)d_in[8];
    const float* bcur = (const float*)d_in[9];
    const int*   src  = (const int*)d_in[11];
    const int*   dst  = (const int*)d_in[12];

    const int N = in_sizes[0] / DIM;
    const int E = in_sizes[11];
    const int L = in_sizes[3] / (DIM * DIM);

    // workspace carve
    const int Npad = (N + 1023) & ~1023;
    int* cnt       = (int*)d_ws;                 // Npad
    int* row_start = cnt + Npad;                 // Npad+64
    int* cursor    = row_start + Npad + 64;      // Npad (also reused as `partial`)
    int* blocksum  = cursor + Npad;              // 1024
    int* csr_src   = blocksum + 1024;            // E
    float* h       = (float*)(csr_src + ((E + 63) & ~63));  // N*192

    float* out_e = (float*)d_out;
    float* out_b = out_e + (size_t)N * DIM;
    float* out_s = out_b + (size_t)N * DIM;

    // ---- build CSR (once per call; reused by both layers) ----
    hipMemsetAsync(cnt, 0, (size_t)N * sizeof(int), stream);
    {
        int blk = 256, grd = (E + blk - 1) / blk;
        k_hist<<<grd, blk, 0, stream>>>(dst, cnt, E);
        int nb = (N + 1023) / 1024;
        k_scan1<<<nb, 1024, 0, stream>>>(cnt, cursor /*partial*/, blocksum, N);
        k_scan2<<<1, 1024, 0, stream>>>(blocksum, nb);
        k_scan3<<<(N + 255) / 256, 256, 0, stream>>>(cursor /*partial*/, blocksum, cnt,
                                                     row_start, cursor, N);
        k_fill<<<grd, blk, 0, stream>>>(src, dst, cursor, csr_src, E);
    }

    const int blkA  = 256;
    const int grdA3 = 1024;                       // fused phase A: grid-stride
    const int totalWaves = grdA3 * (blkA / 64);
    const int grdB  = (N * DIM + blkA - 1) / blkA;  // one wave per node

    for (int l = 0; l < L; ++l) {
        const float* Xe = (l == 0) ? e0 : out_e;
        const float* Xb = (l == 0) ? b0 : out_b;
        const float* Xs = (l == 0) ? s0 : out_s;

        k_phaseA3<<<grdA3, blkA, 0, stream>>>(
            Xe, Xb, Xs,
            We + (size_t)l * DIM * DIM, be + (size_t)l * DIM,
            Wb + (size_t)l * DIM * DIM, bb + (size_t)l * DIM,
            Ws + (size_t)l * DIM * DIM, bs + (size_t)l * DIM,
            h, bcur, N, totalWaves);

        k_phaseB<<<grdB, blkA, 0, stream>>>(h, row_start, csr_src,
                                            out_e, out_b, out_s, bcur, N);
    }
}

// Round 3
// 357.821 us; speedup vs baseline: 2.5379x; 1.1836x over previous
//
#include <hip/hip_runtime.h>
#include <hip/hip_bf16.h>

#define DIM 64

// ---------- wave helpers (wave64) ----------
static __device__ __forceinline__ float bcast_lane(float v, int l) {
    return __uint_as_float(__builtin_amdgcn_readlane(__float_as_uint(v), l));
}

static __device__ __forceinline__ float wave_sum64(float v) {
    v += __shfl_xor(v, 1, 64);
    v += __shfl_xor(v, 2, 64);
    v += __shfl_xor(v, 4, 64);
    v += __shfl_xor(v, 8, 64);
    v += __shfl_xor(v, 16, 64);
    v += __shfl_xor(v, 32, 64);
    return v;
}

static __device__ __forceinline__ float b2f(unsigned short u) {
    return __uint_as_float(((unsigned int)u) << 16);
}
static __device__ __forceinline__ unsigned short f2b(float f) {
    // RNE round to bf16
    unsigned int u = __float_as_uint(f);
    unsigned int rounded = u + 0x7fff + ((u >> 16) & 1);
    return (unsigned short)(rounded >> 16);
}

// ---------- CSR build ----------
__global__ void k_hist(const int* __restrict__ dst, int* __restrict__ cnt, int E) {
    int e = blockIdx.x * blockDim.x + threadIdx.x;
    if (e < E) atomicAdd(&cnt[dst[e]], 1);
}

__global__ __launch_bounds__(1024) void k_scan1(const int* __restrict__ cnt,
                                                int* __restrict__ partial,
                                                int* __restrict__ blocksum, int n) {
    __shared__ int buf[1024];
    int t = threadIdx.x;
    int i = blockIdx.x * 1024 + t;
    int v = (i < n) ? cnt[i] : 0;
    buf[t] = v;
    __syncthreads();
    for (int off = 1; off < 1024; off <<= 1) {
        int x = (t >= off) ? buf[t - off] : 0;
        __syncthreads();
        buf[t] += x;
        __syncthreads();
    }
    if (i < n) partial[i] = buf[t];
    if (t == 1023) blocksum[blockIdx.x] = buf[1023];
}

__global__ __launch_bounds__(1024) void k_scan2(int* __restrict__ blocksum, int nb) {
    __shared__ int buf[1024];
    int t = threadIdx.x;
    buf[t] = (t < nb) ? blocksum[t] : 0;
    __syncthreads();
    for (int off = 1; off < 1024; off <<= 1) {
        int x = (t >= off) ? buf[t - off] : 0;
        __syncthreads();
        buf[t] += x;
        __syncthreads();
    }
    if (t < nb) blocksum[t] = buf[t];
}

__global__ void k_scan3(const int* __restrict__ partial, const int* __restrict__ blocksum,
                        const int* __restrict__ cnt,
                        int* __restrict__ row_start, int* __restrict__ cursor, int n) {
    int i = blockIdx.x * blockDim.x + threadIdx.x;
    if (i == 0) row_start[0] = 0;
    if (i < n) {
        int b = i >> 10;
        int add = (b > 0) ? blocksum[b - 1] : 0;
        int incl = partial[i] + add;
        row_start[i + 1] = incl;
        cursor[i] = incl - cnt[i];
    }
}

__global__ void k_fill(const int* __restrict__ src, const int* __restrict__ dst,
                       int* __restrict__ cursor, int* __restrict__ csr_src, int E) {
    int e = blockIdx.x * blockDim.x + threadIdx.x;
    if (e < E) {
        int p = atomicAdd(&cursor[dst[e]], 1);
        csr_src[p] = src[e];
    }
}

// ---------- Phase A (fused 3 manifolds): pre-op + 64x64 GEMV (+post-op) -> bf16 h ----------
__global__ __launch_bounds__(256) void k_phaseA3(
        const float* __restrict__ Xe, const float* __restrict__ Xb, const float* __restrict__ Xs,
        const float* __restrict__ We, const float* __restrict__ be,
        const float* __restrict__ Wb, const float* __restrict__ bb,
        const float* __restrict__ Ws, const float* __restrict__ bs,
        unsigned short* __restrict__ hb, const float* __restrict__ curv,
        int n, int totalWaves) {
    int gtid = blockIdx.x * blockDim.x + threadIdx.x;
    int gw   = gtid >> 6;
    int lane = gtid & 63;
    float c  = curv[0];
    float sc = sqrtf(c);

    for (int mode = 0; mode < 3; ++mode) {
        const float* W    = (mode == 0) ? We : (mode == 1) ? Wb : Ws;
        const float* bias = (mode == 0) ? be : (mode == 1) ? bb : bs;
        const float* X    = (mode == 0) ? Xe : (mode == 1) ? Xb : Xs;

        float w[DIM];
        const float4* Wv = reinterpret_cast<const float4*>(W + lane * DIM);
#pragma unroll
        for (int q = 0; q < DIM / 4; ++q) {
            float4 t = Wv[q];
            w[4 * q + 0] = t.x; w[4 * q + 1] = t.y;
            w[4 * q + 2] = t.z; w[4 * q + 3] = t.w;
        }
        float bl = bias[lane];

        int node = gw;
        float x = (node < n) ? X[(size_t)node * DIM + lane] : 0.f;
        for (; node < n; node += totalWaves) {
            int nn = node + totalWaves;
            float xn = (nn < n) ? X[(size_t)nn * DIM + lane] : 0.f;  // prefetch

            float xx = x;
            if (mode == 1) {
                float n2 = wave_sum64(xx * xx);
                float dn = fmaxf(sqrtf(n2), 1e-10f);
                float scale = (2.0f / sc) * atanhf(sc * dn) / dn;
                xx *= scale;
            } else if (mode == 2) {
                float n2 = wave_sum64(xx * xx);
                float nr = fmaxf(sqrtf(n2), 1e-12f);
                xx /= nr;
            }

            float a0 = bl, a1 = 0.f, a2 = 0.f, a3 = 0.f;
#pragma unroll
            for (int k = 0; k < DIM; k += 4) {
                a0 = fmaf(bcast_lane(xx, k + 0), w[k + 0], a0);
                a1 = fmaf(bcast_lane(xx, k + 1), w[k + 1], a1);
                a2 = fmaf(bcast_lane(xx, k + 2), w[k + 2], a2);
                a3 = fmaf(bcast_lane(xx, k + 3), w[k + 3], a3);
            }
            float acc = (a0 + a1) + (a2 + a3);

            if (mode == 2) {
                float n2 = wave_sum64(acc * acc);
                float nr = fmaxf(sqrtf(n2), 1e-12f);
                acc /= nr;
            }

            hb[(size_t)node * (3 * DIM) + mode * DIM + lane] = f2b(acc);
            x = xn;
        }
    }
}

// ---------- Phase B: mean-aggregate (bf16 gather) + epilogues ----------
__global__ __launch_bounds__(256) void k_phaseB(const unsigned short* __restrict__ hb,
                                                const int* __restrict__ row_start,
                                                const int* __restrict__ csr_src,
                                                float* __restrict__ e_out,
                                                float* __restrict__ b_out,
                                                float* __restrict__ s_out,
                                                const float* __restrict__ curv,
                                                int n) {
    int gtid = blockIdx.x * blockDim.x + threadIdx.x;
    int wid  = gtid >> 6;
    int lane = gtid & 63;
    if (wid >= n) return;

    int beg = row_start[wid];
    int end = row_start[wid + 1];

    float a0 = 0.f, a1 = 0.f, a2 = 0.f;
    float p0 = 0.f, p1 = 0.f, p2 = 0.f;
    float q0 = 0.f, q1 = 0.f, q2 = 0.f;
    float r0 = 0.f, r1 = 0.f, r2 = 0.f;
    int j = beg;
    for (; j + 3 < end; j += 4) {
        int s0 = csr_src[j];
        int s1 = csr_src[j + 1];
        int s2 = csr_src[j + 2];
        int s3 = csr_src[j + 3];
        const unsigned short* h0 = hb + (size_t)s0 * (3 * DIM);
        const unsigned short* h1 = hb + (size_t)s1 * (3 * DIM);
        const unsigned short* h2 = hb + (size_t)s2 * (3 * DIM);
        const unsigned short* h3 = hb + (size_t)s3 * (3 * DIM);
        unsigned short t00 = h0[lane], t01 = h0[DIM + lane], t02 = h0[2 * DIM + lane];
        unsigned short t10 = h1[lane], t11 = h1[DIM + lane], t12 = h1[2 * DIM + lane];
        unsigned short t20 = h2[lane], t21 = h2[DIM + lane], t22 = h2[2 * DIM + lane];
        unsigned short t30 = h3[lane], t31 = h3[DIM + lane], t32 = h3[2 * DIM + lane];
        a0 += b2f(t00); a1 += b2f(t01); a2 += b2f(t02);
        p0 += b2f(t10); p1 += b2f(t11); p2 += b2f(t12);
        q0 += b2f(t20); q1 += b2f(t21); q2 += b2f(t22);
        r0 += b2f(t30); r1 += b2f(t31); r2 += b2f(t32);
    }
    for (; j < end; ++j) {
        int s0 = csr_src[j];
        const unsigned short* h0 = hb + (size_t)s0 * (3 * DIM);
        a0 += b2f(h0[lane]); a1 += b2f(h0[DIM + lane]); a2 += b2f(h0[2 * DIM + lane]);
    }
    a0 += (p0 + q0) + r0;
    a1 += (p1 + q1) + r1;
    a2 += (p2 + q2) + r2;

    int cnt = end - beg;
    float inv = 1.0f / (float)(cnt > 0 ? cnt : 1);
    a0 *= inv; a1 *= inv; a2 *= inv;

    // euclidean: LeakyReLU(0.2)
    e_out[(size_t)wid * DIM + lane] = (a0 >= 0.f) ? a0 : 0.2f * a0;

    // hyperbolic: exp map at origin
    float c = curv[0];
    float sc = sqrtf(c);
    float vn = fmaxf(sqrtf(wave_sum64(a1 * a1)), 1e-10f);
    float scale = tanhf(sc * vn * 0.5f) / (sc * vn);
    b_out[(size_t)wid * DIM + lane] = a1 * scale;

    // spherical: normalize
    float nr = fmaxf(sqrtf(wave_sum64(a2 * a2)), 1e-12f);
    s_out[(size_t)wid * DIM + lane] = a2 / nr;
}

extern "C" void kernel_launch(void* const* d_in, const int* in_sizes, int n_in,
                              void* d_out, int out_size, void* d_ws, size_t ws_size,
                              hipStream_t stream) {
    const float* e0   = (const float*)d_in[0];
    const float* b0   = (const float*)d_in[1];
    const float* s0   = (const float*)d_in[2];
    const float* We   = (const float*)d_in[3];
    const float* be   = (const float*)d_in[4];
    const float* Wb   = (const float*)d_in[5];
    const float* bb   = (const float*)d_in[6];
    const float* Ws   = (const float*)d_in[7];
    const float* bs   = (const float*)d_in[8];
    const float* bcur = (const float*)d_in[9];
    const int*   src  = (const int*)d_in[11];
    const int*   dst  = (const int*)d_in[12];

    const int N = in_sizes[0] / DIM;
    const int E = in_sizes[11];
    const int L = in_sizes[3] / (DIM * DIM);

    // workspace carve
    const int Npad = (N + 1023) & ~1023;
    int* cnt       = (int*)d_ws;                 // Npad
    int* row_start = cnt + Npad;                 // Npad+64
    int* cursor    = row_start + Npad + 64;      // Npad (reused as `partial`)
    int* blocksum  = cursor + Npad;              // 1024
    int* csr_src   = blocksum + 1024;            // E
    unsigned short* hb = (unsigned short*)(csr_src + ((E + 63) & ~63));  // N*192 bf16

    float* out_e = (float*)d_out;
    float* out_b = out_e + (size_t)N * DIM;
    float* out_s = out_b + (size_t)N * DIM;

    // ---- build CSR (once per call; reused by both layers) ----
    hipMemsetAsync(cnt, 0, (size_t)N * sizeof(int), stream);
    {
        int blk = 256, grd = (E + blk - 1) / blk;
        k_hist<<<grd, blk, 0, stream>>>(dst, cnt, E);
        int nb = (N + 1023) / 1024;
        k_scan1<<<nb, 1024, 0, stream>>>(cnt, cursor /*partial*/, blocksum, N);
        k_scan2<<<1, 1024, 0, stream>>>(blocksum, nb);
        k_scan3<<<(N + 255) / 256, 256, 0, stream>>>(cursor /*partial*/, blocksum, cnt,
                                                     row_start, cursor, N);
        k_fill<<<grd, blk, 0, stream>>>(src, dst, cursor, csr_src, E);
    }

    const int blkA  = 256;
    const int grdA3 = 2048;                        // fused phase A: grid-stride
    const int totalWaves = grdA3 * (blkA / 64);
    const int grdB  = (N * DIM + blkA - 1) / blkA; // one wave per node

    for (int l = 0; l < L; ++l) {
        const float* Xe = (l == 0) ? e0 : out_e;
        const float* Xb = (l == 0) ? b0 : out_b;
        const float* Xs = (l == 0) ? s0 : out_s;

        k_phaseA3<<<grdA3, blkA, 0, stream>>>(
            Xe, Xb, Xs,
            We + (size_t)l * DIM * DIM, be + (size_t)l * DIM,
            Wb + (size_t)l * DIM * DIM, bb + (size_t)l * DIM,
            Ws + (size_t)l * DIM * DIM, bs + (size_t)l * DIM,
            hb, bcur, N, totalWaves);

        k_phaseB<<<grdB, blkA, 0, stream>>>(hb, row_start, csr_src,
                                            out_e, out_b, out_s, bcur, N);
    }
}

// Round 4
// 353.064 us; speedup vs baseline: 2.5721x; 1.0135x over previous
//
#include <hip/hip_runtime.h>
#include <hip/hip_bf16.h>

#define DIM 64

typedef __attribute__((ext_vector_type(16))) float f32x16;

// ---------- wave helpers (wave64) ----------
static __device__ __forceinline__ float wave_sum64(float v) {
    v += __shfl_xor(v, 1, 64);
    v += __shfl_xor(v, 2, 64);
    v += __shfl_xor(v, 4, 64);
    v += __shfl_xor(v, 8, 64);
    v += __shfl_xor(v, 16, 64);
    v += __shfl_xor(v, 32, 64);
    return v;
}

static __device__ __forceinline__ float b2f(unsigned short u) {
    return __uint_as_float(((unsigned int)u) << 16);
}
static __device__ __forceinline__ unsigned short f2b(float f) {
    unsigned int u = __float_as_uint(f);
    unsigned int rounded = u + 0x7fff + ((u >> 16) & 1);
    return (unsigned short)(rounded >> 16);
}

// ---------- CSR build ----------
__global__ void k_hist(const int* __restrict__ dst, int* __restrict__ cnt, int E) {
    int e = blockIdx.x * blockDim.x + threadIdx.x;
    if (e < E) atomicAdd(&cnt[dst[e]], 1);
}

__global__ __launch_bounds__(1024) void k_scan1(const int* __restrict__ cnt,
                                                int* __restrict__ partial,
                                                int* __restrict__ blocksum, int n) {
    __shared__ int buf[1024];
    int t = threadIdx.x;
    int i = blockIdx.x * 1024 + t;
    int v = (i < n) ? cnt[i] : 0;
    buf[t] = v;
    __syncthreads();
    for (int off = 1; off < 1024; off <<= 1) {
        int x = (t >= off) ? buf[t - off] : 0;
        __syncthreads();
        buf[t] += x;
        __syncthreads();
    }
    if (i < n) partial[i] = buf[t];
    if (t == 1023) blocksum[blockIdx.x] = buf[1023];
}

__global__ __launch_bounds__(1024) void k_scan2(int* __restrict__ blocksum, int nb) {
    __shared__ int buf[1024];
    int t = threadIdx.x;
    buf[t] = (t < nb) ? blocksum[t] : 0;
    __syncthreads();
    for (int off = 1; off < 1024; off <<= 1) {
        int x = (t >= off) ? buf[t - off] : 0;
        __syncthreads();
        buf[t] += x;
        __syncthreads();
    }
    if (t < nb) blocksum[t] = buf[t];
}

__global__ void k_scan3(const int* __restrict__ partial, const int* __restrict__ blocksum,
                        const int* __restrict__ cnt,
                        int* __restrict__ row_start, int* __restrict__ cursor, int n) {
    int i = blockIdx.x * blockDim.x + threadIdx.x;
    if (i == 0) row_start[0] = 0;
    if (i < n) {
        int b = i >> 10;
        int add = (b > 0) ? blocksum[b - 1] : 0;
        int incl = partial[i] + add;
        row_start[i + 1] = incl;
        cursor[i] = incl - cnt[i];
    }
}

__global__ void k_fill(const int* __restrict__ src, const int* __restrict__ dst,
                       int* __restrict__ cursor, int* __restrict__ csr_src, int E) {
    int e = blockIdx.x * blockDim.x + threadIdx.x;
    if (e < E) {
        int p = atomicAdd(&cursor[dst[e]], 1);
        csr_src[p] = src[e];
    }
}

// ---------- Phase A ----------
// 16 fmas: s-vector elements [k0..k0+15] times weight quads q0..q3
static __device__ __forceinline__ void fma16(const f32x16& s,
                                             const float4& q0, const float4& q1,
                                             const float4& q2, const float4& q3,
                                             float& a0, float& a1, float& a2, float& a3) {
    a0 = fmaf(s[0],  q0.x, a0); a1 = fmaf(s[1],  q0.y, a1);
    a2 = fmaf(s[2],  q0.z, a2); a3 = fmaf(s[3],  q0.w, a3);
    a0 = fmaf(s[4],  q1.x, a0); a1 = fmaf(s[5],  q1.y, a1);
    a2 = fmaf(s[6],  q1.z, a2); a3 = fmaf(s[7],  q1.w, a3);
    a0 = fmaf(s[8],  q2.x, a0); a1 = fmaf(s[9],  q2.y, a1);
    a2 = fmaf(s[10], q2.z, a2); a3 = fmaf(s[11], q2.w, a3);
    a0 = fmaf(s[12], q3.x, a0); a1 = fmaf(s[13], q3.y, a1);
    a2 = fmaf(s[14], q3.z, a2); a3 = fmaf(s[15], q3.w, a3);
}

// MODE 0: euclidean (identity pre), 1: hyperbolic (log-map pre), 2: spherical (normalize pre+post)
template <int MODE>
static __device__ __forceinline__ void gemv_rows(const float* __restrict__ X,
                                                 const float* __restrict__ W,
                                                 const float* __restrict__ bias,
                                                 unsigned short* __restrict__ hb,
                                                 float sc, int n, int gw, int lane,
                                                 int totalWaves) {
    // lane holds weight row `lane` in 16 float4 registers (compile-time indexed)
    float4 w[16];
    const float4* Wv = reinterpret_cast<const float4*>(W + lane * DIM);
#pragma unroll
    for (int q = 0; q < 16; ++q) w[q] = Wv[q];
    float bl = bias[lane];

    for (int node = gw; node < n; node += totalWaves) {
        int nu = __builtin_amdgcn_readfirstlane(node);
        const float* xp = X + (size_t)nu * DIM;

        // x row -> 64 SGPRs via scalar loads (wave-uniform address)
        f32x16 sa, sb, sd, se;
        asm volatile(
            "s_load_dwordx16 %0, %4, 0x0\n\t"
            "s_load_dwordx16 %1, %4, 0x40\n\t"
            "s_load_dwordx16 %2, %4, 0x80\n\t"
            "s_load_dwordx16 %3, %4, 0xc0\n\t"
            "s_waitcnt lgkmcnt(0)"
            : "=&s"(sa), "=&s"(sb), "=&s"(sd), "=&s"(se)
            : "s"(xp));

        // wave-uniform pre-scale from per-lane copy of x
        float scale = 1.0f;
        if (MODE == 1 || MODE == 2) {
            float xv = xp[lane];
            float n2 = wave_sum64(xv * xv);
            float dn = fmaxf(sqrtf(n2), (MODE == 1) ? 1e-10f : 1e-12f);
            if (MODE == 1) scale = (2.0f / sc) * atanhf(sc * dn) / dn;
            else           scale = 1.0f / dn;
        }

        float a0 = 0.f, a1 = 0.f, a2 = 0.f, a3 = 0.f;
        fma16(sa, w[0],  w[1],  w[2],  w[3],  a0, a1, a2, a3);
        fma16(sb, w[4],  w[5],  w[6],  w[7],  a0, a1, a2, a3);
        fma16(sd, w[8],  w[9],  w[10], w[11], a0, a1, a2, a3);
        fma16(se, w[12], w[13], w[14], w[15], a0, a1, a2, a3);
        float acc = (a0 + a1) + (a2 + a3);
        acc = fmaf(scale, acc, bl);   // out = scale*(x@W^T) + bias

        if (MODE == 2) {
            float n2 = wave_sum64(acc * acc);
            float nr = fmaxf(sqrtf(n2), 1e-12f);
            acc /= nr;
        }

        hb[(size_t)node * (3 * DIM) + MODE * DIM + lane] = f2b(acc);
    }
}

__global__ __launch_bounds__(256) void k_phaseA3(
        const float* __restrict__ Xe, const float* __restrict__ Xb, const float* __restrict__ Xs,
        const float* __restrict__ We, const float* __restrict__ be,
        const float* __restrict__ Wb, const float* __restrict__ bb,
        const float* __restrict__ Ws, const float* __restrict__ bs,
        unsigned short* __restrict__ hb, const float* __restrict__ curv,
        int n, int totalWaves) {
    int gtid = blockIdx.x * blockDim.x + threadIdx.x;
    int gw   = gtid >> 6;
    int lane = gtid & 63;
    float sc = sqrtf(curv[0]);

    gemv_rows<0>(Xe, We, be, hb, sc, n, gw, lane, totalWaves);
    gemv_rows<1>(Xb, Wb, bb, hb, sc, n, gw, lane, totalWaves);
    gemv_rows<2>(Xs, Ws, bs, hb, sc, n, gw, lane, totalWaves);
}

// ---------- Phase B: mean-aggregate (bf16 gather) + epilogues ----------
__global__ __launch_bounds__(256) void k_phaseB(const unsigned short* __restrict__ hb,
                                                const int* __restrict__ row_start,
                                                const int* __restrict__ csr_src,
                                                float* __restrict__ e_out,
                                                float* __restrict__ b_out,
                                                float* __restrict__ s_out,
                                                const float* __restrict__ curv,
                                                int n) {
    int gtid = blockIdx.x * blockDim.x + threadIdx.x;
    int wid  = gtid >> 6;
    int lane = gtid & 63;
    if (wid >= n) return;

    int beg = row_start[wid];
    int end = row_start[wid + 1];

    float a0 = 0.f, a1 = 0.f, a2 = 0.f;
    float p0 = 0.f, p1 = 0.f, p2 = 0.f;
    float q0 = 0.f, q1 = 0.f, q2 = 0.f;
    float r0 = 0.f, r1 = 0.f, r2 = 0.f;
    int j = beg;
    for (; j + 3 < end; j += 4) {
        int s0 = csr_src[j];
        int s1 = csr_src[j + 1];
        int s2 = csr_src[j + 2];
        int s3 = csr_src[j + 3];
        const unsigned short* h0 = hb + (size_t)s0 * (3 * DIM);
        const unsigned short* h1 = hb + (size_t)s1 * (3 * DIM);
        const unsigned short* h2 = hb + (size_t)s2 * (3 * DIM);
        const unsigned short* h3 = hb + (size_t)s3 * (3 * DIM);
        unsigned short t00 = h0[lane], t01 = h0[DIM + lane], t02 = h0[2 * DIM + lane];
        unsigned short t10 = h1[lane], t11 = h1[DIM + lane], t12 = h1[2 * DIM + lane];
        unsigned short t20 = h2[lane], t21 = h2[DIM + lane], t22 = h2[2 * DIM + lane];
        unsigned short t30 = h3[lane], t31 = h3[DIM + lane], t32 = h3[2 * DIM + lane];
        a0 += b2f(t00); a1 += b2f(t01); a2 += b2f(t02);
        p0 += b2f(t10); p1 += b2f(t11); p2 += b2f(t12);
        q0 += b2f(t20); q1 += b2f(t21); q2 += b2f(t22);
        r0 += b2f(t30); r1 += b2f(t31); r2 += b2f(t32);
    }
    for (; j < end; ++j) {
        int s0 = csr_src[j];
        const unsigned short* h0 = hb + (size_t)s0 * (3 * DIM);
        a0 += b2f(h0[lane]); a1 += b2f(h0[DIM + lane]); a2 += b2f(h0[2 * DIM + lane]);
    }
    a0 += (p0 + q0) + r0;
    a1 += (p1 + q1) + r1;
    a2 += (p2 + q2) + r2;

    int cnt = end - beg;
    float inv = 1.0f / (float)(cnt > 0 ? cnt : 1);
    a0 *= inv; a1 *= inv; a2 *= inv;

    e_out[(size_t)wid * DIM + lane] = (a0 >= 0.f) ? a0 : 0.2f * a0;

    float c = curv[0];
    float sc = sqrtf(c);
    float vn = fmaxf(sqrtf(wave_sum64(a1 * a1)), 1e-10f);
    float scale = tanhf(sc * vn * 0.5f) / (sc * vn);
    b_out[(size_t)wid * DIM + lane] = a1 * scale;

    float nr = fmaxf(sqrtf(wave_sum64(a2 * a2)), 1e-12f);
    s_out[(size_t)wid * DIM + lane] = a2 / nr;
}

extern "C" void kernel_launch(void* const* d_in, const int* in_sizes, int n_in,
                              void* d_out, int out_size, void* d_ws, size_t ws_size,
                              hipStream_t stream) {
    const float* e0   = (const float*)d_in[0];
    const float* b0   = (const float*)d_in[1];
    const float* s0   = (const float*)d_in[2];
    const float* We   = (const float*)d_in[3];
    const float* be   = (const float*)d_in[4];
    const float* Wb   = (const float*)d_in[5];
    const float* bb   = (const float*)d_in[6];
    const float* Ws   = (const float*)d_in[7];
    const float* bs   = (const float*)d_in[8];
    const float* bcur = (const float*)d_in[9];
    const int*   src  = (const int*)d_in[11];
    const int*   dst  = (const int*)d_in[12];

    const int N = in_sizes[0] / DIM;
    const int E = in_sizes[11];
    const int L = in_sizes[3] / (DIM * DIM);

    // workspace carve
    const int Npad = (N + 1023) & ~1023;
    int* cnt       = (int*)d_ws;                 // Npad
    int* row_start = cnt + Npad;                 // Npad+64
    int* cursor    = row_start + Npad + 64;      // Npad (reused as `partial`)
    int* blocksum  = cursor + Npad;              // 1024
    int* csr_src   = blocksum + 1024;            // E
    unsigned short* hb = (unsigned short*)(csr_src + ((E + 63) & ~63));  // N*192 bf16

    float* out_e = (float*)d_out;
    float* out_b = out_e + (size_t)N * DIM;
    float* out_s = out_b + (size_t)N * DIM;

    // ---- build CSR (once per call; reused by both layers) ----
    hipMemsetAsync(cnt, 0, (size_t)N * sizeof(int), stream);
    {
        int blk = 256, grd = (E + blk - 1) / blk;
        k_hist<<<grd, blk, 0, stream>>>(dst, cnt, E);
        int nb = (N + 1023) / 1024;
        k_scan1<<<nb, 1024, 0, stream>>>(cnt, cursor /*partial*/, blocksum, N);
        k_scan2<<<1, 1024, 0, stream>>>(blocksum, nb);
        k_scan3<<<(N + 255) / 256, 256, 0, stream>>>(cursor /*partial*/, blocksum, cnt,
                                                     row_start, cursor, N);
        k_fill<<<grd, blk, 0, stream>>>(src, dst, cursor, csr_src, E);
    }

    const int blkA  = 256;
    const int grdA3 = 2048;                        // fused phase A: grid-stride
    const int totalWaves = grdA3 * (blkA / 64);
    const int grdB  = (N * DIM + blkA - 1) / blkA; // one wave per node

    for (int l = 0; l < L; ++l) {
        const float* Xe = (l == 0) ? e0 : out_e;
        const float* Xb = (l == 0) ? b0 : out_b;
        const float* Xs = (l == 0) ? s0 : out_s;

        k_phaseA3<<<grdA3, blkA, 0, stream>>>(
            Xe, Xb, Xs,
            We + (size_t)l * DIM * DIM, be + (size_t)l * DIM,
            Wb + (size_t)l * DIM * DIM, bb + (size_t)l * DIM,
            Ws + (size_t)l * DIM * DIM, bs + (size_t)l * DIM,
            hb, bcur, N, totalWaves);

        k_phaseB<<<grdB, blkA, 0, stream>>>(hb, row_start, csr_src,
                                            out_e, out_b, out_s, bcur, N);
    }
}

// Round 5
// 255.737 us; speedup vs baseline: 3.5510x; 1.3806x over previous
//
#include <hip/hip_runtime.h>
#include <hip/hip_bf16.h>

#define DIM 64

typedef __attribute__((ext_vector_type(4)))  float f32x4;
typedef __attribute__((ext_vector_type(8)))  short short8;

// ---------- wave helpers (wave64) ----------
static __device__ __forceinline__ float wave_sum64(float v) {
    v += __shfl_xor(v, 1, 64);
    v += __shfl_xor(v, 2, 64);
    v += __shfl_xor(v, 4, 64);
    v += __shfl_xor(v, 8, 64);
    v += __shfl_xor(v, 16, 64);
    v += __shfl_xor(v, 32, 64);
    return v;
}

static __device__ __forceinline__ float b2f(unsigned short u) {
    return __uint_as_float(((unsigned int)u) << 16);
}
static __device__ __forceinline__ unsigned short f2b(float f) {
    unsigned int u = __float_as_uint(f);
    unsigned int rounded = u + 0x7fff + ((u >> 16) & 1);
    return (unsigned short)(rounded >> 16);
}

// ---------- CSR build ----------
__global__ void k_hist(const int* __restrict__ dst, int* __restrict__ cnt, int E) {
    int e = blockIdx.x * blockDim.x + threadIdx.x;
    if (e < E) atomicAdd(&cnt[dst[e]], 1);
}

__global__ __launch_bounds__(1024) void k_scan1(const int* __restrict__ cnt,
                                                int* __restrict__ partial,
                                                int* __restrict__ blocksum, int n) {
    __shared__ int buf[1024];
    int t = threadIdx.x;
    int i = blockIdx.x * 1024 + t;
    int v = (i < n) ? cnt[i] : 0;
    buf[t] = v;
    __syncthreads();
    for (int off = 1; off < 1024; off <<= 1) {
        int x = (t >= off) ? buf[t - off] : 0;
        __syncthreads();
        buf[t] += x;
        __syncthreads();
    }
    if (i < n) partial[i] = buf[t];
    if (t == 1023) blocksum[blockIdx.x] = buf[1023];
}

__global__ __launch_bounds__(1024) void k_scan2(int* __restrict__ blocksum, int nb) {
    __shared__ int buf[1024];
    int t = threadIdx.x;
    buf[t] = (t < nb) ? blocksum[t] : 0;
    __syncthreads();
    for (int off = 1; off < 1024; off <<= 1) {
        int x = (t >= off) ? buf[t - off] : 0;
        __syncthreads();
        buf[t] += x;
        __syncthreads();
    }
    if (t < nb) blocksum[t] = buf[t];
}

__global__ void k_scan3(const int* __restrict__ partial, const int* __restrict__ blocksum,
                        const int* __restrict__ cnt,
                        int* __restrict__ row_start, int* __restrict__ cursor, int n) {
    int i = blockIdx.x * blockDim.x + threadIdx.x;
    if (i == 0) row_start[0] = 0;
    if (i < n) {
        int b = i >> 10;
        int add = (b > 0) ? blocksum[b - 1] : 0;
        int incl = partial[i] + add;
        row_start[i + 1] = incl;
        cursor[i] = incl - cnt[i];
    }
}

__global__ void k_fill(const int* __restrict__ src, const int* __restrict__ dst,
                       int* __restrict__ cursor, int* __restrict__ csr_src, int E) {
    int e = blockIdx.x * blockDim.x + threadIdx.x;
    if (e < E) {
        int p = atomicAdd(&cursor[dst[e]], 1);
        csr_src[p] = src[e];
    }
}

// ---------- W pre-convert: f32 -> bf16 hi/lo planes ----------
// layout: wcvt[ ((l*3 + mode)*2 + plane) * 4096 + row*64 + k ]  (bf16 as ushort)
__global__ void k_wconv(const float* __restrict__ We, const float* __restrict__ Wb,
                        const float* __restrict__ Ws, unsigned short* __restrict__ wcvt,
                        int L) {
    int i = blockIdx.x * blockDim.x + threadIdx.x;
    int total = L * 3 * 4096;
    if (i >= total) return;
    int pos  = i & 4095;
    int lm   = i >> 12;          // l*3 + mode
    int mode = lm % 3;
    int l    = lm / 3;
    const float* W = (mode == 0) ? We : (mode == 1) ? Wb : Ws;
    float v = W[(size_t)l * 4096 + pos];
    unsigned short hi = f2b(v);
    unsigned short lo = f2b(v - b2f(hi));
    wcvt[((size_t)lm * 2 + 0) * 4096 + pos] = hi;
    wcvt[((size_t)lm * 2 + 1) * 4096 + pos] = lo;
}

// ---------- Phase A via MFMA ----------
// One wave per (mode, 16-node tile). h = scale_pre(x) @ W^T + bias, optional post-normalize.
// A-frag (16x16x32 bf16): lane l holds A[m=l&15][k=8*(l>>4)+i], i=0..7
// B-frag:                 lane l holds B[k=8*(l>>4)+i][n=l&15]  = W[n][k]
// D:                      lane l holds D[row=(l>>4)*4+r][col=l&15], r=0..3
__global__ __launch_bounds__(256) void k_phaseA_mfma(
        const float* __restrict__ Xe, const float* __restrict__ Xb, const float* __restrict__ Xs,
        const unsigned short* __restrict__ wcvt,  // for this layer: base at l*3*2*4096
        const float* __restrict__ be, const float* __restrict__ bb, const float* __restrict__ bs,
        unsigned short* __restrict__ hb, const float* __restrict__ curv,
        int n, int ntiles) {
    int gtid = blockIdx.x * blockDim.x + threadIdx.x;
    int wid  = gtid >> 6;
    int lane = gtid & 63;
    int work = 3 * ntiles;
    if (wid >= work) return;

    int mode  = wid / ntiles;
    int tile  = wid - mode * ntiles;
    int node0 = tile * 16;
    int mrow  = lane & 15;
    int half  = lane >> 4;

    const float* X    = (mode == 0) ? Xe : (mode == 1) ? Xb : Xs;
    const float* bias = (mode == 0) ? be : (mode == 1) ? bb : bs;
    float sc = sqrtf(curv[0]);

    // ---- load x row fragment: 16 f32 (k = 8*half..+7 and 32+8*half..+7) ----
    int row = node0 + mrow;
    int rowc = (row < n) ? row : (n - 1);
    const float* xp = X + (size_t)rowc * DIM + 8 * half;
    float xv[16];
    {
        const float4* p0 = reinterpret_cast<const float4*>(xp);
        const float4* p1 = reinterpret_cast<const float4*>(xp + 32);
        float4 a = p0[0], b = p0[1], c = p1[0], d = p1[1];
        xv[0]=a.x; xv[1]=a.y; xv[2]=a.z; xv[3]=a.w;
        xv[4]=b.x; xv[5]=b.y; xv[6]=b.z; xv[7]=b.w;
        xv[8]=c.x; xv[9]=c.y; xv[10]=c.z; xv[11]=c.w;
        xv[12]=d.x; xv[13]=d.y; xv[14]=d.z; xv[15]=d.w;
    }

    // ---- per-row norm (4-lane-group reduce over `half`) + pre-scale ----
    float scale = 1.0f;
    if (mode != 0) {
        float ss = 0.f;
#pragma unroll
        for (int i = 0; i < 16; ++i) ss = fmaf(xv[i], xv[i], ss);
        ss += __shfl_xor(ss, 16, 64);
        ss += __shfl_xor(ss, 32, 64);
        if (mode == 1) {
            float dn = fmaxf(sqrtf(ss), 1e-10f);
            scale = (2.0f / sc) * atanhf(sc * dn) / dn;
        } else {
            float dn = fmaxf(sqrtf(ss), 1e-12f);
            scale = 1.0f / dn;
        }
    }

    // ---- scaled x -> bf16 hi/lo A-frags ----
    short8 a_hi0, a_hi1, a_lo0, a_lo1;
#pragma unroll
    for (int i = 0; i < 8; ++i) {
        float s0 = xv[i] * scale;
        unsigned short h0 = f2b(s0);
        a_hi0[i] = (short)h0;
        a_lo0[i] = (short)f2b(s0 - b2f(h0));
        float s1 = xv[8 + i] * scale;
        unsigned short h1 = f2b(s1);
        a_hi1[i] = (short)h1;
        a_lo1[i] = (short)f2b(s1 - b2f(h1));
    }

    // ---- B-frags from pre-converted W planes ----
    // b[t][kc] lane l elem i = W[16t+mrow][32kc + 8*half + i]
    const unsigned short* whi = wcvt + ((size_t)mode * 2 + 0) * 4096;
    const unsigned short* wlo = wcvt + ((size_t)mode * 2 + 1) * 4096;
    short8 b_hi[4][2], b_lo[4][2];
#pragma unroll
    for (int t = 0; t < 4; ++t) {
        int wrow = 16 * t + mrow;
#pragma unroll
        for (int kc = 0; kc < 2; ++kc) {
            int off = wrow * DIM + 32 * kc + 8 * half;
            b_hi[t][kc] = *reinterpret_cast<const short8*>(whi + off);
            b_lo[t][kc] = *reinterpret_cast<const short8*>(wlo + off);
        }
    }

    // ---- MFMA: acc[t] = A·B[t], 3 split products ----
    f32x4 acc[4];
#pragma unroll
    for (int t = 0; t < 4; ++t) {
        f32x4 a = {0.f, 0.f, 0.f, 0.f};
        a = __builtin_amdgcn_mfma_f32_16x16x32_bf16(a_hi0, b_hi[t][0], a, 0, 0, 0);
        a = __builtin_amdgcn_mfma_f32_16x16x32_bf16(a_hi1, b_hi[t][1], a, 0, 0, 0);
        a = __builtin_amdgcn_mfma_f32_16x16x32_bf16(a_lo0, b_hi[t][0], a, 0, 0, 0);
        a = __builtin_amdgcn_mfma_f32_16x16x32_bf16(a_lo1, b_hi[t][1], a, 0, 0, 0);
        a = __builtin_amdgcn_mfma_f32_16x16x32_bf16(a_hi0, b_lo[t][0], a, 0, 0, 0);
        a = __builtin_amdgcn_mfma_f32_16x16x32_bf16(a_hi1, b_lo[t][1], a, 0, 0, 0);
        acc[t] = a;
    }

    // ---- epilogue: bias, optional post-normalize, store bf16 ----
    float v[4][4];   // [t][r]
#pragma unroll
    for (int t = 0; t < 4; ++t) {
        float bl = bias[16 * t + mrow];
#pragma unroll
        for (int r = 0; r < 4; ++r) v[t][r] = acc[t][r] + bl;
    }

    if (mode == 2) {
#pragma unroll
        for (int r = 0; r < 4; ++r) {
            float s = v[0][r]*v[0][r] + v[1][r]*v[1][r] + v[2][r]*v[2][r] + v[3][r]*v[3][r];
            s += __shfl_xor(s, 1, 64);
            s += __shfl_xor(s, 2, 64);
            s += __shfl_xor(s, 4, 64);
            s += __shfl_xor(s, 8, 64);
            float inv = 1.0f / fmaxf(sqrtf(s), 1e-12f);
#pragma unroll
            for (int t = 0; t < 4; ++t) v[t][r] *= inv;
        }
    }

#pragma unroll
    for (int r = 0; r < 4; ++r) {
        int orow = node0 + half * 4 + r;
        if (orow < n) {
            unsigned short* op = hb + (size_t)orow * (3 * DIM) + mode * DIM + mrow;
#pragma unroll
            for (int t = 0; t < 4; ++t) op[16 * t] = f2b(v[t][r]);
        }
    }
}

// ---------- Phase B: mean-aggregate (bf16 gather) + epilogues ----------
__global__ __launch_bounds__(256) void k_phaseB(const unsigned short* __restrict__ hb,
                                                const int* __restrict__ row_start,
                                                const int* __restrict__ csr_src,
                                                float* __restrict__ e_out,
                                                float* __restrict__ b_out,
                                                float* __restrict__ s_out,
                                                const float* __restrict__ curv,
                                                int n) {
    int gtid = blockIdx.x * blockDim.x + threadIdx.x;
    int wid  = gtid >> 6;
    int lane = gtid & 63;
    if (wid >= n) return;

    int beg = row_start[wid];
    int end = row_start[wid + 1];

    float a0 = 0.f, a1 = 0.f, a2 = 0.f;
    float p0 = 0.f, p1 = 0.f, p2 = 0.f;
    float q0 = 0.f, q1 = 0.f, q2 = 0.f;
    float r0 = 0.f, r1 = 0.f, r2 = 0.f;
    int j = beg;
    for (; j + 3 < end; j += 4) {
        int s0 = csr_src[j];
        int s1 = csr_src[j + 1];
        int s2 = csr_src[j + 2];
        int s3 = csr_src[j + 3];
        const unsigned short* h0 = hb + (size_t)s0 * (3 * DIM);
        const unsigned short* h1 = hb + (size_t)s1 * (3 * DIM);
        const unsigned short* h2 = hb + (size_t)s2 * (3 * DIM);
        const unsigned short* h3 = hb + (size_t)s3 * (3 * DIM);
        unsigned short t00 = h0[lane], t01 = h0[DIM + lane], t02 = h0[2 * DIM + lane];
        unsigned short t10 = h1[lane], t11 = h1[DIM + lane], t12 = h1[2 * DIM + lane];
        unsigned short t20 = h2[lane], t21 = h2[DIM + lane], t22 = h2[2 * DIM + lane];
        unsigned short t30 = h3[lane], t31 = h3[DIM + lane], t32 = h3[2 * DIM + lane];
        a0 += b2f(t00); a1 += b2f(t01); a2 += b2f(t02);
        p0 += b2f(t10); p1 += b2f(t11); p2 += b2f(t12);
        q0 += b2f(t20); q1 += b2f(t21); q2 += b2f(t22);
        r0 += b2f(t30); r1 += b2f(t31); r2 += b2f(t32);
    }
    for (; j < end; ++j) {
        int s0 = csr_src[j];
        const unsigned short* h0 = hb + (size_t)s0 * (3 * DIM);
        a0 += b2f(h0[lane]); a1 += b2f(h0[DIM + lane]); a2 += b2f(h0[2 * DIM + lane]);
    }
    a0 += (p0 + q0) + r0;
    a1 += (p1 + q1) + r1;
    a2 += (p2 + q2) + r2;

    int cnt = end - beg;
    float inv = 1.0f / (float)(cnt > 0 ? cnt : 1);
    a0 *= inv; a1 *= inv; a2 *= inv;

    e_out[(size_t)wid * DIM + lane] = (a0 >= 0.f) ? a0 : 0.2f * a0;

    float c = curv[0];
    float sc = sqrtf(c);
    float vn = fmaxf(sqrtf(wave_sum64(a1 * a1)), 1e-10f);
    float scale = tanhf(sc * vn * 0.5f) / (sc * vn);
    b_out[(size_t)wid * DIM + lane] = a1 * scale;

    float nr = fmaxf(sqrtf(wave_sum64(a2 * a2)), 1e-12f);
    s_out[(size_t)wid * DIM + lane] = a2 / nr;
}

extern "C" void kernel_launch(void* const* d_in, const int* in_sizes, int n_in,
                              void* d_out, int out_size, void* d_ws, size_t ws_size,
                              hipStream_t stream) {
    const float* e0   = (const float*)d_in[0];
    const float* b0   = (const float*)d_in[1];
    const float* s0   = (const float*)d_in[2];
    const float* We   = (const float*)d_in[3];
    const float* be   = (const float*)d_in[4];
    const float* Wb   = (const float*)d_in[5];
    const float* bb   = (const float*)d_in[6];
    const float* Ws   = (const float*)d_in[7];
    const float* bs   = (const float*)d_in[8];
    const float* bcur = (const float*)d_in[9];
    const int*   src  = (const int*)d_in[11];
    const int*   dst  = (const int*)d_in[12];

    const int N = in_sizes[0] / DIM;
    const int E = in_sizes[11];
    const int L = in_sizes[3] / (DIM * DIM);

    // workspace carve
    const int Npad = (N + 1023) & ~1023;
    int* cnt       = (int*)d_ws;                  // Npad
    int* row_start = cnt + Npad;                  // Npad+64
    int* cursor    = row_start + Npad + 64;       // Npad (reused as `partial`)
    int* blocksum  = cursor + Npad;               // 1024
    int* csr_src   = blocksum + 1024;             // E
    unsigned short* hb   = (unsigned short*)(csr_src + ((E + 63) & ~63));   // N*192 bf16
    unsigned short* wcvt = hb + (size_t)N * 192;  // L*3*2*4096 bf16

    float* out_e = (float*)d_out;
    float* out_b = out_e + (size_t)N * DIM;
    float* out_s = out_b + (size_t)N * DIM;

    // ---- build CSR + W convert (once per call) ----
    hipMemsetAsync(cnt, 0, (size_t)N * sizeof(int), stream);
    {
        int blk = 256, grd = (E + blk - 1) / blk;
        k_hist<<<grd, blk, 0, stream>>>(dst, cnt, E);
        int nb = (N + 1023) / 1024;
        k_scan1<<<nb, 1024, 0, stream>>>(cnt, cursor /*partial*/, blocksum, N);
        k_scan2<<<1, 1024, 0, stream>>>(blocksum, nb);
        k_scan3<<<(N + 255) / 256, 256, 0, stream>>>(cursor /*partial*/, blocksum, cnt,
                                                     row_start, cursor, N);
        k_fill<<<grd, blk, 0, stream>>>(src, dst, cursor, csr_src, E);

        int wtot = L * 3 * 4096;
        k_wconv<<<(wtot + 255) / 256, 256, 0, stream>>>(We, Wb, Ws, wcvt, L);
    }

    const int ntiles = (N + 15) / 16;
    const int waves  = 3 * ntiles;
    const int grdA   = (waves + 3) / 4;            // 4 waves per 256-thr block
    const int grdB   = (N * DIM + 255) / 256;      // one wave per node

    for (int l = 0; l < L; ++l) {
        const float* Xe = (l == 0) ? e0 : out_e;
        const float* Xb = (l == 0) ? b0 : out_b;
        const float* Xs = (l == 0) ? s0 : out_s;

        k_phaseA_mfma<<<grdA, 256, 0, stream>>>(
            Xe, Xb, Xs,
            wcvt + (size_t)l * 3 * 2 * 4096,
            be + (size_t)l * DIM, bb + (size_t)l * DIM, bs + (size_t)l * DIM,
            hb, bcur, N, ntiles);

        k_phaseB<<<grdB, 256, 0, stream>>>(hb, row_start, csr_src,
                                           out_e, out_b, out_s, bcur, N);
    }
}

// Round 6
// 255.489 us; speedup vs baseline: 3.5544x; 1.0010x over previous
//
#include <hip/hip_runtime.h>
#include <hip/hip_bf16.h>

#define DIM 64

typedef __attribute__((ext_vector_type(4)))  float f32x4;
typedef __attribute__((ext_vector_type(8)))  short short8;

// ---------- wave helpers (wave64) ----------
static __device__ __forceinline__ float wave_sum64(float v) {
    v += __shfl_xor(v, 1, 64);
    v += __shfl_xor(v, 2, 64);
    v += __shfl_xor(v, 4, 64);
    v += __shfl_xor(v, 8, 64);
    v += __shfl_xor(v, 16, 64);
    v += __shfl_xor(v, 32, 64);
    return v;
}

static __device__ __forceinline__ float b2f(unsigned short u) {
    return __uint_as_float(((unsigned int)u) << 16);
}
static __device__ __forceinline__ unsigned short f2b(float f) {
    unsigned int u = __float_as_uint(f);
    unsigned int rounded = u + 0x7fff + ((u >> 16) & 1);
    return (unsigned short)(rounded >> 16);
}
// bf16 pair in a u32 -> two floats
static __device__ __forceinline__ float b2f_lo(unsigned int u) {
    return __uint_as_float(u << 16);
}
static __device__ __forceinline__ float b2f_hi(unsigned int u) {
    return __uint_as_float(u & 0xffff0000u);
}

// ---------- CSR build ----------
__global__ void k_hist(const int* __restrict__ dst, int* __restrict__ cnt, int E) {
    int e = blockIdx.x * blockDim.x + threadIdx.x;
    if (e < E) atomicAdd(&cnt[dst[e]], 1);
}

__global__ __launch_bounds__(1024) void k_scan1(const int* __restrict__ cnt,
                                                int* __restrict__ partial,
                                                int* __restrict__ blocksum, int n) {
    __shared__ int buf[1024];
    int t = threadIdx.x;
    int i = blockIdx.x * 1024 + t;
    int v = (i < n) ? cnt[i] : 0;
    buf[t] = v;
    __syncthreads();
    for (int off = 1; off < 1024; off <<= 1) {
        int x = (t >= off) ? buf[t - off] : 0;
        __syncthreads();
        buf[t] += x;
        __syncthreads();
    }
    if (i < n) partial[i] = buf[t];
    if (t == 1023) blocksum[blockIdx.x] = buf[1023];
}

__global__ __launch_bounds__(1024) void k_scan2(int* __restrict__ blocksum, int nb) {
    __shared__ int buf[1024];
    int t = threadIdx.x;
    buf[t] = (t < nb) ? blocksum[t] : 0;
    __syncthreads();
    for (int off = 1; off < 1024; off <<= 1) {
        int x = (t >= off) ? buf[t - off] : 0;
        __syncthreads();
        buf[t] += x;
        __syncthreads();
    }
    if (t < nb) blocksum[t] = buf[t];
}

__global__ void k_scan3(const int* __restrict__ partial, const int* __restrict__ blocksum,
                        const int* __restrict__ cnt,
                        int* __restrict__ row_start, int* __restrict__ cursor, int n) {
    int i = blockIdx.x * blockDim.x + threadIdx.x;
    if (i == 0) row_start[0] = 0;
    if (i < n) {
        int b = i >> 10;
        int add = (b > 0) ? blocksum[b - 1] : 0;
        int incl = partial[i] + add;
        row_start[i + 1] = incl;
        cursor[i] = incl - cnt[i];
    }
}

__global__ void k_fill(const int* __restrict__ src, const int* __restrict__ dst,
                       int* __restrict__ cursor, int* __restrict__ csr_src, int E) {
    int e = blockIdx.x * blockDim.x + threadIdx.x;
    if (e < E) {
        int p = atomicAdd(&cursor[dst[e]], 1);
        csr_src[p] = src[e];
    }
}

// ---------- W pre-convert: f32 -> bf16 hi/lo planes ----------
__global__ void k_wconv(const float* __restrict__ We, const float* __restrict__ Wb,
                        const float* __restrict__ Ws, unsigned short* __restrict__ wcvt,
                        int L) {
    int i = blockIdx.x * blockDim.x + threadIdx.x;
    int total = L * 3 * 4096;
    if (i >= total) return;
    int pos  = i & 4095;
    int lm   = i >> 12;          // l*3 + mode
    int mode = lm % 3;
    int l    = lm / 3;
    const float* W = (mode == 0) ? We : (mode == 1) ? Wb : Ws;
    float v = W[(size_t)l * 4096 + pos];
    unsigned short hi = f2b(v);
    unsigned short lo = f2b(v - b2f(hi));
    wcvt[((size_t)lm * 2 + 0) * 4096 + pos] = hi;
    wcvt[((size_t)lm * 2 + 1) * 4096 + pos] = lo;
}

// ---------- Phase A via MFMA (unchanged from round 5) ----------
__global__ __launch_bounds__(256) void k_phaseA_mfma(
        const float* __restrict__ Xe, const float* __restrict__ Xb, const float* __restrict__ Xs,
        const unsigned short* __restrict__ wcvt,
        const float* __restrict__ be, const float* __restrict__ bb, const float* __restrict__ bs,
        unsigned short* __restrict__ hb, const float* __restrict__ curv,
        int n, int ntiles) {
    int gtid = blockIdx.x * blockDim.x + threadIdx.x;
    int wid  = gtid >> 6;
    int lane = gtid & 63;
    int work = 3 * ntiles;
    if (wid >= work) return;

    int mode  = wid / ntiles;
    int tile  = wid - mode * ntiles;
    int node0 = tile * 16;
    int mrow  = lane & 15;
    int half  = lane >> 4;

    const float* X    = (mode == 0) ? Xe : (mode == 1) ? Xb : Xs;
    const float* bias = (mode == 0) ? be : (mode == 1) ? bb : bs;
    float sc = sqrtf(curv[0]);

    int row = node0 + mrow;
    int rowc = (row < n) ? row : (n - 1);
    const float* xp = X + (size_t)rowc * DIM + 8 * half;
    float xv[16];
    {
        const float4* p0 = reinterpret_cast<const float4*>(xp);
        const float4* p1 = reinterpret_cast<const float4*>(xp + 32);
        float4 a = p0[0], b = p0[1], c = p1[0], d = p1[1];
        xv[0]=a.x; xv[1]=a.y; xv[2]=a.z; xv[3]=a.w;
        xv[4]=b.x; xv[5]=b.y; xv[6]=b.z; xv[7]=b.w;
        xv[8]=c.x; xv[9]=c.y; xv[10]=c.z; xv[11]=c.w;
        xv[12]=d.x; xv[13]=d.y; xv[14]=d.z; xv[15]=d.w;
    }

    float scale = 1.0f;
    if (mode != 0) {
        float ss = 0.f;
#pragma unroll
        for (int i = 0; i < 16; ++i) ss = fmaf(xv[i], xv[i], ss);
        ss += __shfl_xor(ss, 16, 64);
        ss += __shfl_xor(ss, 32, 64);
        if (mode == 1) {
            float dn = fmaxf(sqrtf(ss), 1e-10f);
            scale = (2.0f / sc) * atanhf(sc * dn) / dn;
        } else {
            float dn = fmaxf(sqrtf(ss), 1e-12f);
            scale = 1.0f / dn;
        }
    }

    short8 a_hi0, a_hi1, a_lo0, a_lo1;
#pragma unroll
    for (int i = 0; i < 8; ++i) {
        float s0 = xv[i] * scale;
        unsigned short h0 = f2b(s0);
        a_hi0[i] = (short)h0;
        a_lo0[i] = (short)f2b(s0 - b2f(h0));
        float s1 = xv[8 + i] * scale;
        unsigned short h1 = f2b(s1);
        a_hi1[i] = (short)h1;
        a_lo1[i] = (short)f2b(s1 - b2f(h1));
    }

    const unsigned short* whi = wcvt + ((size_t)mode * 2 + 0) * 4096;
    const unsigned short* wlo = wcvt + ((size_t)mode * 2 + 1) * 4096;
    short8 b_hi[4][2], b_lo[4][2];
#pragma unroll
    for (int t = 0; t < 4; ++t) {
        int wrow = 16 * t + mrow;
#pragma unroll
        for (int kc = 0; kc < 2; ++kc) {
            int off = wrow * DIM + 32 * kc + 8 * half;
            b_hi[t][kc] = *reinterpret_cast<const short8*>(whi + off);
            b_lo[t][kc] = *reinterpret_cast<const short8*>(wlo + off);
        }
    }

    f32x4 acc[4];
#pragma unroll
    for (int t = 0; t < 4; ++t) {
        f32x4 a = {0.f, 0.f, 0.f, 0.f};
        a = __builtin_amdgcn_mfma_f32_16x16x32_bf16(a_hi0, b_hi[t][0], a, 0, 0, 0);
        a = __builtin_amdgcn_mfma_f32_16x16x32_bf16(a_hi1, b_hi[t][1], a, 0, 0, 0);
        a = __builtin_amdgcn_mfma_f32_16x16x32_bf16(a_lo0, b_hi[t][0], a, 0, 0, 0);
        a = __builtin_amdgcn_mfma_f32_16x16x32_bf16(a_lo1, b_hi[t][1], a, 0, 0, 0);
        a = __builtin_amdgcn_mfma_f32_16x16x32_bf16(a_hi0, b_lo[t][0], a, 0, 0, 0);
        a = __builtin_amdgcn_mfma_f32_16x16x32_bf16(a_hi1, b_lo[t][1], a, 0, 0, 0);
        acc[t] = a;
    }

    float v[4][4];
#pragma unroll
    for (int t = 0; t < 4; ++t) {
        float bl = bias[16 * t + mrow];
#pragma unroll
        for (int r = 0; r < 4; ++r) v[t][r] = acc[t][r] + bl;
    }

    if (mode == 2) {
#pragma unroll
        for (int r = 0; r < 4; ++r) {
            float s = v[0][r]*v[0][r] + v[1][r]*v[1][r] + v[2][r]*v[2][r] + v[3][r]*v[3][r];
            s += __shfl_xor(s, 1, 64);
            s += __shfl_xor(s, 2, 64);
            s += __shfl_xor(s, 4, 64);
            s += __shfl_xor(s, 8, 64);
            float inv = 1.0f / fmaxf(sqrtf(s), 1e-12f);
#pragma unroll
            for (int t = 0; t < 4; ++t) v[t][r] *= inv;
        }
    }

#pragma unroll
    for (int r = 0; r < 4; ++r) {
        int orow = node0 + half * 4 + r;
        if (orow < n) {
            unsigned short* op = hb + (size_t)orow * (3 * DIM) + mode * DIM + mrow;
#pragma unroll
            for (int t = 0; t < 4; ++t) op[16 * t] = f2b(v[t][r]);
        }
    }
}

// ---------- Phase B: one dwordx2 per edge (48 active lanes), LDS redistribute ----------
__global__ __launch_bounds__(256) void k_phaseB(const unsigned short* __restrict__ hb,
                                                const int* __restrict__ row_start,
                                                const int* __restrict__ csr_src,
                                                float* __restrict__ e_out,
                                                float* __restrict__ b_out,
                                                float* __restrict__ s_out,
                                                const float* __restrict__ curv,
                                                int n) {
    __shared__ float smem[4][192];
    int gtid = blockIdx.x * blockDim.x + threadIdx.x;
    int wid  = gtid >> 6;
    int lane = threadIdx.x & 63;
    int w    = threadIdx.x >> 6;
    if (wid >= n) return;

    int beg = row_start[wid];
    int end = row_start[wid + 1];

    const char* base = (const char*)hb;
    const size_t myoff = (size_t)lane * 8;   // lane < 48 covers the 384B row
    bool active = lane < 48;

    // 4 accumulator quads (4-edge unroll); each lane owns flattened feats [4*lane, 4*lane+4)
    float a0=0.f,a1=0.f,a2=0.f,a3=0.f;
    float b0=0.f,b1=0.f,b2=0.f,b3=0.f;
    float c0=0.f,c1=0.f,c2=0.f,c3=0.f;
    float d0=0.f,d1=0.f,d2=0.f,d3=0.f;

    int j = beg;
    if (active) {
        for (; j + 3 < end; j += 4) {
            int s0 = csr_src[j];
            int s1 = csr_src[j + 1];
            int s2 = csr_src[j + 2];
            int s3 = csr_src[j + 3];
            uint2 v0 = *(const uint2*)(base + (size_t)s0 * 384 + myoff);
            uint2 v1 = *(const uint2*)(base + (size_t)s1 * 384 + myoff);
            uint2 v2 = *(const uint2*)(base + (size_t)s2 * 384 + myoff);
            uint2 v3 = *(const uint2*)(base + (size_t)s3 * 384 + myoff);
            a0 += b2f_lo(v0.x); a1 += b2f_hi(v0.x); a2 += b2f_lo(v0.y); a3 += b2f_hi(v0.y);
            b0 += b2f_lo(v1.x); b1 += b2f_hi(v1.x); b2 += b2f_lo(v1.y); b3 += b2f_hi(v1.y);
            c0 += b2f_lo(v2.x); c1 += b2f_hi(v2.x); c2 += b2f_lo(v2.y); c3 += b2f_hi(v2.y);
            d0 += b2f_lo(v3.x); d1 += b2f_hi(v3.x); d2 += b2f_lo(v3.y); d3 += b2f_hi(v3.y);
        }
        for (; j < end; ++j) {
            int s0 = csr_src[j];
            uint2 v0 = *(const uint2*)(base + (size_t)s0 * 384 + myoff);
            a0 += b2f_lo(v0.x); a1 += b2f_hi(v0.x); a2 += b2f_lo(v0.y); a3 += b2f_hi(v0.y);
        }
        a0 += (b0 + c0) + d0;
        a1 += (b1 + c1) + d1;
        a2 += (b2 + c2) + d2;
        a3 += (b3 + c3) + d3;

        // hi-part conversion gave value*2^16? No: b2f_hi keeps the bf16 already in the
        // high halfword position -> correct float. (b2f_lo shifts the low halfword up.)
        smem[w][4 * lane + 0] = a0;
        smem[w][4 * lane + 1] = a1;
        smem[w][4 * lane + 2] = a2;
        smem[w][4 * lane + 3] = a3;
    }
    // wave-local LDS fence: writes above visible to all lanes of THIS wave
    asm volatile("s_waitcnt lgkmcnt(0)" ::: "memory");

    float fe = smem[w][lane];
    float fb = smem[w][64 + lane];
    float fs = smem[w][128 + lane];

    int cnt = end - beg;
    float inv = 1.0f / (float)(cnt > 0 ? cnt : 1);
    fe *= inv; fb *= inv; fs *= inv;

    // euclidean: LeakyReLU(0.2)
    e_out[(size_t)wid * DIM + lane] = (fe >= 0.f) ? fe : 0.2f * fe;

    // hyperbolic: exp map at origin
    float c = curv[0];
    float sc = sqrtf(c);
    float vn = fmaxf(sqrtf(wave_sum64(fb * fb)), 1e-10f);
    float scale = tanhf(sc * vn * 0.5f) / (sc * vn);
    b_out[(size_t)wid * DIM + lane] = fb * scale;

    // spherical: normalize
    float nr = fmaxf(sqrtf(wave_sum64(fs * fs)), 1e-12f);
    s_out[(size_t)wid * DIM + lane] = fs / nr;
}

extern "C" void kernel_launch(void* const* d_in, const int* in_sizes, int n_in,
                              void* d_out, int out_size, void* d_ws, size_t ws_size,
                              hipStream_t stream) {
    const float* e0   = (const float*)d_in[0];
    const float* b0   = (const float*)d_in[1];
    const float* s0   = (const float*)d_in[2];
    const float* We   = (const float*)d_in[3];
    const float* be   = (const float*)d_in[4];
    const float* Wb   = (const float*)d_in[5];
    const float* bb   = (const float*)d_in[6];
    const float* Ws   = (const float*)d_in[7];
    const float* bs   = (const float*)d_in[8];
    const float* bcur = (const float*)d_in[9];
    const int*   src  = (const int*)d_in[11];
    const int*   dst  = (const int*)d_in[12];

    const int N = in_sizes[0] / DIM;
    const int E = in_sizes[11];
    const int L = in_sizes[3] / (DIM * DIM);

    // workspace carve
    const int Npad = (N + 1023) & ~1023;
    int* cnt       = (int*)d_ws;                  // Npad
    int* row_start = cnt + Npad;                  // Npad+64
    int* cursor    = row_start + Npad + 64;       // Npad (reused as `partial`)
    int* blocksum  = cursor + Npad;               // 1024
    int* csr_src   = blocksum + 1024;             // E
    unsigned short* hb   = (unsigned short*)(csr_src + ((E + 63) & ~63));   // N*192 bf16
    unsigned short* wcvt = hb + (size_t)N * 192;  // L*3*2*4096 bf16

    float* out_e = (float*)d_out;
    float* out_b = out_e + (size_t)N * DIM;
    float* out_s = out_b + (size_t)N * DIM;

    // ---- build CSR + W convert (once per call) ----
    hipMemsetAsync(cnt, 0, (size_t)N * sizeof(int), stream);
    {
        int blk = 256, grd = (E + blk - 1) / blk;
        k_hist<<<grd, blk, 0, stream>>>(dst, cnt, E);
        int nb = (N + 1023) / 1024;
        k_scan1<<<nb, 1024, 0, stream>>>(cnt, cursor /*partial*/, blocksum, N);
        k_scan2<<<1, 1024, 0, stream>>>(blocksum, nb);
        k_scan3<<<(N + 255) / 256, 256, 0, stream>>>(cursor /*partial*/, blocksum, cnt,
                                                     row_start, cursor, N);
        k_fill<<<grd, blk, 0, stream>>>(src, dst, cursor, csr_src, E);

        int wtot = L * 3 * 4096;
        k_wconv<<<(wtot + 255) / 256, 256, 0, stream>>>(We, Wb, Ws, wcvt, L);
    }

    const int ntiles = (N + 15) / 16;
    const int waves  = 3 * ntiles;
    const int grdA   = (waves + 3) / 4;            // 4 waves per 256-thr block
    const int grdB   = (N * DIM + 255) / 256;      // one wave per node

    for (int l = 0; l < L; ++l) {
        const float* Xe = (l == 0) ? e0 : out_e;
        const float* Xb = (l == 0) ? b0 : out_b;
        const float* Xs = (l == 0) ? s0 : out_s;

        k_phaseA_mfma<<<grdA, 256, 0, stream>>>(
            Xe, Xb, Xs,
            wcvt + (size_t)l * 3 * 2 * 4096,
            be + (size_t)l * DIM, bb + (size_t)l * DIM, bs + (size_t)l * DIM,
            hb, bcur, N, ntiles);

        k_phaseB<<<grdB, 256, 0, stream>>>(hb, row_start, csr_src,
                                           out_e, out_b, out_s, bcur, N);
    }
}

// Round 7
// 235.638 us; speedup vs baseline: 3.8539x; 1.0842x over previous
//
#include <hip/hip_runtime.h>
#include <hip/hip_bf16.h>

#define DIM 64

typedef __attribute__((ext_vector_type(4)))  float f32x4;
typedef __attribute__((ext_vector_type(8)))  short short8;
typedef __attribute__((ext_vector_type(4)))  unsigned short u16x4;

// ---------- wave helpers (wave64) ----------
static __device__ __forceinline__ float wave_sum64(float v) {
    v += __shfl_xor(v, 1, 64);
    v += __shfl_xor(v, 2, 64);
    v += __shfl_xor(v, 4, 64);
    v += __shfl_xor(v, 8, 64);
    v += __shfl_xor(v, 16, 64);
    v += __shfl_xor(v, 32, 64);
    return v;
}

static __device__ __forceinline__ float b2f(unsigned short u) {
    return __uint_as_float(((unsigned int)u) << 16);
}
static __device__ __forceinline__ unsigned short f2b(float f) {
    unsigned int u = __float_as_uint(f);
    unsigned int rounded = u + 0x7fff + ((u >> 16) & 1);
    return (unsigned short)(rounded >> 16);
}
static __device__ __forceinline__ float b2f_lo(unsigned int u) {
    return __uint_as_float(u << 16);
}
static __device__ __forceinline__ float b2f_hi(unsigned int u) {
    return __uint_as_float(u & 0xffff0000u);
}

// ---------- CSR build ----------
__global__ void k_hist(const int* __restrict__ dst, int* __restrict__ cnt, int E) {
    int e = blockIdx.x * blockDim.x + threadIdx.x;
    if (e < E) atomicAdd(&cnt[dst[e]], 1);
}

__global__ __launch_bounds__(1024) void k_scan1(const int* __restrict__ cnt,
                                                int* __restrict__ partial,
                                                int* __restrict__ blocksum, int n) {
    __shared__ int buf[1024];
    int t = threadIdx.x;
    int i = blockIdx.x * 1024 + t;
    int v = (i < n) ? cnt[i] : 0;
    buf[t] = v;
    __syncthreads();
    for (int off = 1; off < 1024; off <<= 1) {
        int x = (t >= off) ? buf[t - off] : 0;
        __syncthreads();
        buf[t] += x;
        __syncthreads();
    }
    if (i < n) partial[i] = buf[t];
    if (t == 1023) blocksum[blockIdx.x] = buf[1023];
}

__global__ __launch_bounds__(1024) void k_scan2(int* __restrict__ blocksum, int nb) {
    __shared__ int buf[1024];
    int t = threadIdx.x;
    buf[t] = (t < nb) ? blocksum[t] : 0;
    __syncthreads();
    for (int off = 1; off < 1024; off <<= 1) {
        int x = (t >= off) ? buf[t - off] : 0;
        __syncthreads();
        buf[t] += x;
        __syncthreads();
    }
    if (t < nb) blocksum[t] = buf[t];
}

__global__ void k_scan3(const int* __restrict__ partial, const int* __restrict__ blocksum,
                        const int* __restrict__ cnt,
                        int* __restrict__ row_start, int* __restrict__ cursor, int n) {
    int i = blockIdx.x * blockDim.x + threadIdx.x;
    if (i == 0) row_start[0] = 0;
    if (i < n) {
        int b = i >> 10;
        int add = (b > 0) ? blocksum[b - 1] : 0;
        int incl = partial[i] + add;
        row_start[i + 1] = incl;
        cursor[i] = incl - cnt[i];
    }
}

__global__ void k_fill(const int* __restrict__ src, const int* __restrict__ dst,
                       int* __restrict__ cursor, int* __restrict__ csr_src, int E) {
    int e = blockIdx.x * blockDim.x + threadIdx.x;
    if (e < E) {
        int p = atomicAdd(&cursor[dst[e]], 1);
        csr_src[p] = src[e];
    }
}

// ---------- W pre-convert: f32 -> bf16 hi/lo planes ----------
__global__ void k_wconv(const float* __restrict__ We, const float* __restrict__ Wb,
                        const float* __restrict__ Ws, unsigned short* __restrict__ wcvt,
                        int L) {
    int i = blockIdx.x * blockDim.x + threadIdx.x;
    int total = L * 3 * 4096;
    if (i >= total) return;
    int pos  = i & 4095;
    int lm   = i >> 12;          // l*3 + mode
    int mode = lm % 3;
    int l    = lm / 3;
    const float* W = (mode == 0) ? We : (mode == 1) ? Wb : Ws;
    float v = W[(size_t)l * 4096 + pos];
    unsigned short hi = f2b(v);
    unsigned short lo = f2b(v - b2f(hi));
    wcvt[((size_t)lm * 2 + 0) * 4096 + pos] = hi;
    wcvt[((size_t)lm * 2 + 1) * 4096 + pos] = lo;
}

// ---------- Phase A via MFMA, grid-stride tiles, packed stores ----------
// hb column order within a mode is PERMUTED: packed col c = 4*mrow + t holds
// feature f = 16*t + mrow  (f = 16*(c&3) + (c>>2); c = 4*(f&15) + (f>>4)).
// Aggregation is per-column so the permutation commutes; phaseB un-permutes.
__global__ __launch_bounds__(256) void k_phaseA_mfma(
        const float* __restrict__ Xe, const float* __restrict__ Xb, const float* __restrict__ Xs,
        const unsigned short* __restrict__ wcvt,
        const float* __restrict__ be, const float* __restrict__ bb, const float* __restrict__ bs,
        unsigned short* __restrict__ hb, const float* __restrict__ curv,
        int n, int ntiles, int wavesPerMode) {
    int gtid = blockIdx.x * blockDim.x + threadIdx.x;
    int gw   = gtid >> 6;
    int lane = gtid & 63;
    int mode = gw / wavesPerMode;
    if (mode >= 3) return;
    int w0   = gw - mode * wavesPerMode;

    int mrow  = lane & 15;
    int half  = lane >> 4;

    const float* X    = (mode == 0) ? Xe : (mode == 1) ? Xb : Xs;
    const float* bias = (mode == 0) ? be : (mode == 1) ? bb : bs;
    float sc = sqrtf(curv[0]);

    // B-frags + bias: loaded once, reused across tiles
    const unsigned short* whi = wcvt + ((size_t)mode * 2 + 0) * 4096;
    const unsigned short* wlo = wcvt + ((size_t)mode * 2 + 1) * 4096;
    short8 b_hi[4][2], b_lo[4][2];
#pragma unroll
    for (int t = 0; t < 4; ++t) {
        int wrow = 16 * t + mrow;
#pragma unroll
        for (int kc = 0; kc < 2; ++kc) {
            int off = wrow * DIM + 32 * kc + 8 * half;
            b_hi[t][kc] = *reinterpret_cast<const short8*>(whi + off);
            b_lo[t][kc] = *reinterpret_cast<const short8*>(wlo + off);
        }
    }
    float bl[4];
#pragma unroll
    for (int t = 0; t < 4; ++t) bl[t] = bias[16 * t + mrow];

    for (int tile = w0; tile < ntiles; tile += wavesPerMode) {
        int node0 = tile * 16;
        int row = node0 + mrow;
        int rowc = (row < n) ? row : (n - 1);
        const float* xp = X + (size_t)rowc * DIM + 8 * half;
        float xv[16];
        {
            const float4* p0 = reinterpret_cast<const float4*>(xp);
            const float4* p1 = reinterpret_cast<const float4*>(xp + 32);
            float4 a = p0[0], b = p0[1], c = p1[0], d = p1[1];
            xv[0]=a.x; xv[1]=a.y; xv[2]=a.z; xv[3]=a.w;
            xv[4]=b.x; xv[5]=b.y; xv[6]=b.z; xv[7]=b.w;
            xv[8]=c.x; xv[9]=c.y; xv[10]=c.z; xv[11]=c.w;
            xv[12]=d.x; xv[13]=d.y; xv[14]=d.z; xv[15]=d.w;
        }

        float scale = 1.0f;
        if (mode != 0) {
            float ss = 0.f;
#pragma unroll
            for (int i = 0; i < 16; ++i) ss = fmaf(xv[i], xv[i], ss);
            ss += __shfl_xor(ss, 16, 64);
            ss += __shfl_xor(ss, 32, 64);
            if (mode == 1) {
                float dn = fmaxf(sqrtf(ss), 1e-10f);
                scale = (2.0f / sc) * atanhf(sc * dn) / dn;
            } else {
                float dn = fmaxf(sqrtf(ss), 1e-12f);
                scale = 1.0f / dn;
            }
        }

        short8 a_hi0, a_hi1, a_lo0, a_lo1;
#pragma unroll
        for (int i = 0; i < 8; ++i) {
            float s0 = xv[i] * scale;
            unsigned short h0 = f2b(s0);
            a_hi0[i] = (short)h0;
            a_lo0[i] = (short)f2b(s0 - b2f(h0));
            float s1 = xv[8 + i] * scale;
            unsigned short h1 = f2b(s1);
            a_hi1[i] = (short)h1;
            a_lo1[i] = (short)f2b(s1 - b2f(h1));
        }

        f32x4 acc[4];
#pragma unroll
        for (int t = 0; t < 4; ++t) {
            f32x4 a = {0.f, 0.f, 0.f, 0.f};
            a = __builtin_amdgcn_mfma_f32_16x16x32_bf16(a_hi0, b_hi[t][0], a, 0, 0, 0);
            a = __builtin_amdgcn_mfma_f32_16x16x32_bf16(a_hi1, b_hi[t][1], a, 0, 0, 0);
            a = __builtin_amdgcn_mfma_f32_16x16x32_bf16(a_lo0, b_hi[t][0], a, 0, 0, 0);
            a = __builtin_amdgcn_mfma_f32_16x16x32_bf16(a_lo1, b_hi[t][1], a, 0, 0, 0);
            a = __builtin_amdgcn_mfma_f32_16x16x32_bf16(a_hi0, b_lo[t][0], a, 0, 0, 0);
            a = __builtin_amdgcn_mfma_f32_16x16x32_bf16(a_hi1, b_lo[t][1], a, 0, 0, 0);
            acc[t] = a;
        }

        float v[4][4];
#pragma unroll
        for (int t = 0; t < 4; ++t) {
#pragma unroll
            for (int r = 0; r < 4; ++r) v[t][r] = acc[t][r] + bl[t];
        }

        if (mode == 2) {
#pragma unroll
            for (int r = 0; r < 4; ++r) {
                float s = v[0][r]*v[0][r] + v[1][r]*v[1][r] + v[2][r]*v[2][r] + v[3][r]*v[3][r];
                s += __shfl_xor(s, 1, 64);
                s += __shfl_xor(s, 2, 64);
                s += __shfl_xor(s, 4, 64);
                s += __shfl_xor(s, 8, 64);
                float inv = 1.0f / fmaxf(sqrtf(s), 1e-12f);
#pragma unroll
                for (int t = 0; t < 4; ++t) v[t][r] *= inv;
            }
        }

        // packed store: one 8B store per r (cols 4*mrow..4*mrow+3, permuted order)
#pragma unroll
        for (int r = 0; r < 4; ++r) {
            int orow = node0 + half * 4 + r;
            if (orow < n) {
                u16x4 pk;
                pk.x = f2b(v[0][r]); pk.y = f2b(v[1][r]);
                pk.z = f2b(v[2][r]); pk.w = f2b(v[3][r]);
                *reinterpret_cast<u16x4*>(hb + (size_t)orow * 192 + mode * 64 + 4 * mrow) = pk;
            }
        }
    }
}

// ---------- Phase B: 16-edge batches (16 gathers in flight), LDS redistribute ----------
__global__ __launch_bounds__(256) void k_phaseB(const unsigned short* __restrict__ hb,
                                                const int* __restrict__ row_start,
                                                const int* __restrict__ csr_src,
                                                float* __restrict__ e_out,
                                                float* __restrict__ b_out,
                                                float* __restrict__ s_out,
                                                const float* __restrict__ curv,
                                                int n) {
    __shared__ float smem[4][192];
    int gtid = blockIdx.x * blockDim.x + threadIdx.x;
    int wid  = gtid >> 6;
    int lane = threadIdx.x & 63;
    int w    = threadIdx.x >> 6;
    if (wid >= n) return;

    int beg = row_start[wid];
    int end = row_start[wid + 1];

    const char* base = (const char*)hb;
    const size_t myoff = (size_t)lane * 8;   // lanes 0..47 cover the 384B row
    bool active = lane < 48;

    float a0 = 0.f, a1 = 0.f, a2 = 0.f, a3 = 0.f;

    if (active) {
        for (int j = beg; j < end; j += 16) {
            // one coalesced load fetches 16 indices; clamp tail to end-1
            int li = j + (lane & 15);
            li = (li < end) ? li : (end - 1);
            unsigned int idxv = (unsigned int)csr_src[li];

            uint2 vv[16];
#pragma unroll
            for (int i = 0; i < 16; ++i) {
                unsigned int sidx = __builtin_amdgcn_readlane(idxv, i);
                vv[i] = *(const uint2*)(base + (size_t)sidx * 384 + myoff);
            }
#pragma unroll
            for (int i = 0; i < 16; ++i) {
                float m = (j + i < end) ? 1.0f : 0.0f;   // wave-uniform predicate
                a0 = fmaf(b2f_lo(vv[i].x), m, a0);
                a1 = fmaf(b2f_hi(vv[i].x), m, a1);
                a2 = fmaf(b2f_lo(vv[i].y), m, a2);
                a3 = fmaf(b2f_hi(vv[i].y), m, a3);
            }
        }
        smem[w][4 * lane + 0] = a0;
        smem[w][4 * lane + 1] = a1;
        smem[w][4 * lane + 2] = a2;
        smem[w][4 * lane + 3] = a3;
    }
    // wave-local LDS fence (no cross-wave dependency -> no barrier needed)
    asm volatile("s_waitcnt lgkmcnt(0)" ::: "memory");

    // un-permute: packed col c holds feature f=16*(c&3)+(c>>2); c(f)=4*(f&15)+(f>>4)
    int c = 4 * (lane & 15) + (lane >> 4);
    float fe = smem[w][c];
    float fb = smem[w][64 + c];
    float fs = smem[w][128 + c];

    int cnt = end - beg;
    float inv = 1.0f / (float)(cnt > 0 ? cnt : 1);
    fe *= inv; fb *= inv; fs *= inv;

    e_out[(size_t)wid * DIM + lane] = (fe >= 0.f) ? fe : 0.2f * fe;

    float cc = curv[0];
    float sc = sqrtf(cc);
    float vn = fmaxf(sqrtf(wave_sum64(fb * fb)), 1e-10f);
    float scale = tanhf(sc * vn * 0.5f) / (sc * vn);
    b_out[(size_t)wid * DIM + lane] = fb * scale;

    float nr = fmaxf(sqrtf(wave_sum64(fs * fs)), 1e-12f);
    s_out[(size_t)wid * DIM + lane] = fs / nr;
}

extern "C" void kernel_launch(void* const* d_in, const int* in_sizes, int n_in,
                              void* d_out, int out_size, void* d_ws, size_t ws_size,
                              hipStream_t stream) {
    const float* e0   = (const float*)d_in[0];
    const float* b0   = (const float*)d_in[1];
    const float* s0   = (const float*)d_in[2];
    const float* We   = (const float*)d_in[3];
    const float* be   = (const float*)d_in[4];
    const float* Wb   = (const float*)d_in[5];
    const float* bb   = (const float*)d_in[6];
    const float* Ws   = (const float*)d_in[7];
    const float* bs   = (const float*)d_in[8];
    const float* bcur = (const float*)d_in[9];
    const int*   src  = (const int*)d_in[11];
    const int*   dst  = (const int*)d_in[12];

    const int N = in_sizes[0] / DIM;
    const int E = in_sizes[11];
    const int L = in_sizes[3] / (DIM * DIM);

    // workspace carve
    const int Npad = (N + 1023) & ~1023;
    int* cnt       = (int*)d_ws;                  // Npad
    int* row_start = cnt + Npad;                  // Npad+64
    int* cursor    = row_start + Npad + 64;       // Npad (reused as `partial`)
    int* blocksum  = cursor + Npad;               // 1024
    int* csr_src   = blocksum + 1024;             // E
    unsigned short* hb   = (unsigned short*)(csr_src + ((E + 63) & ~63));   // N*192 bf16
    unsigned short* wcvt = hb + (size_t)N * 192;  // L*3*2*4096 bf16

    float* out_e = (float*)d_out;
    float* out_b = out_e + (size_t)N * DIM;
    float* out_s = out_b + (size_t)N * DIM;

    // ---- build CSR + W convert (once per call) ----
    hipMemsetAsync(cnt, 0, (size_t)N * sizeof(int), stream);
    {
        int blk = 256, grd = (E + blk - 1) / blk;
        k_hist<<<grd, blk, 0, stream>>>(dst, cnt, E);
        int nb = (N + 1023) / 1024;
        k_scan1<<<nb, 1024, 0, stream>>>(cnt, cursor /*partial*/, blocksum, N);
        k_scan2<<<1, 1024, 0, stream>>>(blocksum, nb);
        k_scan3<<<(N + 255) / 256, 256, 0, stream>>>(cursor /*partial*/, blocksum, cnt,
                                                     row_start, cursor, N);
        k_fill<<<grd, blk, 0, stream>>>(src, dst, cursor, csr_src, E);

        int wtot = L * 3 * 4096;
        k_wconv<<<(wtot + 255) / 256, 256, 0, stream>>>(We, Wb, Ws, wcvt, L);
    }

    const int ntiles = (N + 15) / 16;
    const int wavesPerMode = 1024;
    const int grdA   = (3 * wavesPerMode) / 4;     // 4 waves per 256-thr block
    const int grdB   = (N * DIM + 255) / 256;      // one wave per node

    for (int l = 0; l < L; ++l) {
        const float* Xe = (l == 0) ? e0 : out_e;
        const float* Xb = (l == 0) ? b0 : out_b;
        const float* Xs = (l == 0) ? s0 : out_s;

        k_phaseA_mfma<<<grdA, 256, 0, stream>>>(
            Xe, Xb, Xs,
            wcvt + (size_t)l * 3 * 2 * 4096,
            be + (size_t)l * DIM, bb + (size_t)l * DIM, bs + (size_t)l * DIM,
            hb, bcur, N, ntiles, wavesPerMode);

        k_phaseB<<<grdB, 256, 0, stream>>>(hb, row_start, csr_src,
                                           out_e, out_b, out_s, bcur, N);
    }
}